// Round 12
// baseline (742.687 us; speedup 1.0000x reference)
//
#include <hip/hip_runtime.h>
#include <hip/hip_bf16.h>
#include <stdint.h>

typedef __attribute__((ext_vector_type(8))) short short8;
typedef __attribute__((ext_vector_type(4))) short short4_t;
typedef __attribute__((ext_vector_type(4))) float f32x4;
typedef unsigned short u16;
typedef unsigned int u32;

#define C_ 512

__device__ __forceinline__ u16 f2b(float f){
  u32 u = __float_as_uint(f);
  u += 0x7FFFu + ((u >> 16) & 1u);
  return (u16)(u >> 16);
}
__device__ __forceinline__ float b2f(u16 h){ return __uint_as_float(((u32)h) << 16); }

__device__ __forceinline__ u16 f2b_n(float f){
  __hip_bfloat16 b = __float2bfloat16(f);
  return *reinterpret_cast<u16*>(&b);
}

__device__ __forceinline__ short8 cvt8v(f32x4 lo, f32x4 hi){
  short8 r;
  r[0]=(short)f2b_n(lo[0]); r[1]=(short)f2b_n(lo[1]); r[2]=(short)f2b_n(lo[2]); r[3]=(short)f2b_n(lo[3]);
  r[4]=(short)f2b_n(hi[0]); r[5]=(short)f2b_n(hi[1]); r[6]=(short)f2b_n(hi[2]); r[7]=(short)f2b_n(hi[3]);
  return r;
}

// ---------------- prep: k2/v2 = agent @ W + b (reps>1 = probe mode) ----------------
__global__ __launch_bounds__(256) void prep_kv(
    const float* __restrict__ agent_k, const float* __restrict__ Wk, const float* __restrict__ bk,
    const float* __restrict__ agent_v, const float* __restrict__ Wv, const float* __restrict__ bv,
    float* __restrict__ k2, float* __restrict__ v2, u32* __restrict__ gcount, int reps)
{
  const int kv = blockIdx.x >> 6;
  const int c0 = (blockIdx.x & 63) * 8;
  const int t = threadIdx.x;
  const float* ag = kv ? agent_v : agent_k;
  const float* W  = kv ? Wv : Wk;
  const float* bb = kv ? bv : bk;
  float* dst      = kv ? v2 : k2;

  if (blockIdx.x == 0 && t == 0) *gcount = 0u;   // init for pass_a's last-block gate

  __shared__ float ash[16*512];
  __shared__ float part[32][16][8];

  for (int r = 0; r < reps; ++r) {
    for (int i = t; i < 8192; i += 256) ash[i] = ag[i];
    __syncthreads();
    const int cl = t & 7, ks = t >> 3;
    float s[16];
    #pragma unroll
    for (int a = 0; a < 16; ++a) s[a] = 0.f;
    #pragma unroll
    for (int i = 0; i < 16; ++i) {
      const int cc = ks*16 + i;
      const float wv = W[(size_t)cc*C_ + c0 + cl];
      #pragma unroll
      for (int a = 0; a < 16; ++a) s[a] += ash[a*512 + cc] * wv;
    }
    #pragma unroll
    for (int a = 0; a < 16; ++a) part[ks][a][cl] = s[a];
    __syncthreads();
    if (t < 128) {
      const int a = t >> 3, c = t & 7;
      float v = bb[c0 + c];
      #pragma unroll
      for (int k = 0; k < 32; ++k) v += part[k][a][c];
      dst[a*C_ + c0 + c] = v;
    }
    __syncthreads();
  }
}

// merged: blocks 0..511 -> WqkTr, blocks 512..639 -> WvpTr  (reps>1 = probe mode)
__global__ __launch_bounds__(256) void prep_w(
    const float* __restrict__ Wq, const float* __restrict__ bq, const float* __restrict__ k2,
    const float* __restrict__ Wp, const float* __restrict__ v2,
    u16* __restrict__ WqkTr, float* __restrict__ bqk, u16* __restrict__ WvpTr, int reps)
{
  const int bx = blockIdx.x;
  __shared__ float vsh[64];
  for (int r = 0; r < reps; ++r) {
    if (bx < 512) {
      const int t = threadIdx.x;
      if (t < 128) {
        const int c = bx, h = t >> 4, a = t & 15;
        const f32x4* wq4 = (const f32x4*)(Wq + (size_t)c*C_ + h*64);
        const f32x4* k24 = (const f32x4*)(k2 + (size_t)a*C_ + h*64);
        float s = 0.f;
        #pragma unroll
        for (int d4 = 0; d4 < 16; ++d4) {
          f32x4 wv = wq4[d4], kv = k24[d4];
          s += wv[0]*kv[0] + wv[1]*kv[1] + wv[2]*kv[2] + wv[3]*kv[3];
        }
        const int kt = c >> 5, rg = (c >> 3) & 3, e = c & 7;
        const int ct = t >> 4, la = t & 15;
        WqkTr[(((kt*8 + ct)*64) + rg*16 + la)*8 + e] = f2b(s * 0.125f);
        if (c == 0){
          const f32x4* bq4 = (const f32x4*)(bq + h*64);
          float sb = 0.f;
          #pragma unroll
          for (int d4 = 0; d4 < 16; ++d4) {
            f32x4 wv = bq4[d4], kv = k24[d4];
            sb += wv[0]*kv[0] + wv[1]*kv[1] + wv[2]*kv[2] + wv[3]*kv[3];
          }
          bqk[t] = sb * 0.125f;
        }
      }
    } else {
      const int ha = bx - 512, h = ha >> 4, a = ha & 15;
      if (threadIdx.x < 64) vsh[threadIdx.x] = v2[a*C_ + h*64 + threadIdx.x];
      __syncthreads();
      const int kt = ha >> 5, rg = (ha >> 3) & 3, e = ha & 7;
      for (int co = threadIdx.x; co < C_; co += 256){
        float s = 0.f;
        #pragma unroll
        for (int d = 0; d < 64; ++d) s += vsh[d] * Wp[(size_t)(h*64 + d)*C_ + co];
        const int cb = co >> 7, ct = (co >> 4) & 7, la = co & 15;
        WvpTr[((((cb*4 + kt)*8 + ct)*64) + rg*16 + la)*8 + e] = f2b(s);
      }
      __syncthreads();
    }
  }
}

// ---------------- pass A: fragment-linear B in LDS, nt x-loads, last-block gate ----------------
__global__ __launch_bounds__(256, 4) void pass_a(
    const float* __restrict__ x, const u16* __restrict__ WqkTr,
    const float* __restrict__ bqk, u16* __restrict__ attn,
    float* __restrict__ gpart, const float* __restrict__ ca_w1,
    const float* __restrict__ ca_w2, float* __restrict__ gate, u32* __restrict__ gcount)
{
  __shared__ __align__(16) u16 Bs[16384];
  __shared__ float ps[4][16], pm[4][16];
  __shared__ int lastf;

  const int t = threadIdx.x;
  const int m0 = blockIdx.x * 128;
  const int w = t >> 6, lane = t & 63;
  const int la = lane & 15, rg = lane >> 4;

  const float* xr0 = x + (size_t)(m0 + w*32 + la)*C_ + rg*8;
  const float* xr1 = xr0 + 16*C_;

  f32x4 acc[2][8];
  #pragma unroll
  for (int i = 0; i < 2; ++i)
    #pragma unroll
    for (int j = 0; j < 8; ++j) acc[i][j] = (f32x4){0.f,0.f,0.f,0.f};

  f32x4 pr0[2][2], pr1[2][2];
#define LOADKT(slot, kt) \
  pr0[slot][0] = __builtin_nontemporal_load((const f32x4*)(xr0 + (kt)*32));     \
  pr0[slot][1] = __builtin_nontemporal_load((const f32x4*)(xr0 + (kt)*32 + 4)); \
  pr1[slot][0] = __builtin_nontemporal_load((const f32x4*)(xr1 + (kt)*32));     \
  pr1[slot][1] = __builtin_nontemporal_load((const f32x4*)(xr1 + (kt)*32 + 4));

  LOADKT(0, 0); LOADKT(1, 1);

  #pragma unroll
  for (int ph = 0; ph < 4; ++ph) {
    __syncthreads();
    {
      const short8* gs = (const short8*)WqkTr + ph*2048 + t;
      short8* ld = (short8*)Bs + t;
      #pragma unroll
      for (int i = 0; i < 8; ++i) ld[i*256] = gs[i*256];
    }
    __syncthreads();
    #pragma unroll
    for (int k4 = 0; k4 < 4; ++k4) {
      const int kt = ph*4 + k4;
      const int sl = kt & 1;
      short8 b0 = cvt8v(pr0[sl][0], pr0[sl][1]);
      short8 b1 = cvt8v(pr1[sl][0], pr1[sl][1]);
      if (kt < 14) { LOADKT(sl, kt + 2); }
      const u16* fb = Bs + (size_t)k4*4096 + lane*8;
      #pragma unroll
      for (int ct = 0; ct < 8; ++ct) {
        short8 af = *(const short8*)(fb + ct*512);
        acc[0][ct] = __builtin_amdgcn_mfma_f32_16x16x32_bf16(af, b0, acc[0][ct], 0, 0, 0);
        acc[1][ct] = __builtin_amdgcn_mfma_f32_16x16x32_bf16(af, b1, acc[1][ct], 0, 0, 0);
      }
    }
  }
#undef LOADKT

  float psj[4] = {0.f,0.f,0.f,0.f};
  float pmj[4] = {0.f,0.f,0.f,0.f};

  #pragma unroll
  for (int nt = 0; nt < 2; ++nt) {
    const int row = m0 + w*32 + nt*16 + la;
    #pragma unroll
    for (int ct = 0; ct < 8; ++ct) {
      const f32x4 bb = *(const f32x4*)(bqk + ct*16 + rg*4);
      float e0 = __expf(acc[nt][ct][0] + bb[0]);
      float e1 = __expf(acc[nt][ct][1] + bb[1]);
      float e2 = __expf(acc[nt][ct][2] + bb[2]);
      float e3 = __expf(acc[nt][ct][3] + bb[3]);
      float s = e0 + e1 + e2 + e3;
      s += __shfl_xor(s, 16); s += __shfl_xor(s, 32);
      float r = __builtin_amdgcn_rcpf(s);
      float p0 = e0*r, p1 = e1*r, p2 = e2*r, p3 = e3*r;
      psj[0] += p0; psj[1] += p1; psj[2] += p2; psj[3] += p3;
      pmj[0] = fmaxf(pmj[0], p0); pmj[1] = fmaxf(pmj[1], p1);
      pmj[2] = fmaxf(pmj[2], p2); pmj[3] = fmaxf(pmj[3], p3);
      short4_t st;
      st[0]=(short)f2b(p0); st[1]=(short)f2b(p1); st[2]=(short)f2b(p2); st[3]=(short)f2b(p3);
      *(short4_t*)(attn + (size_t)row*128 + ct*16 + rg*4) = st;
    }
  }

  #pragma unroll
  for (int j = 0; j < 4; ++j) {
    float s = psj[j], m = pmj[j];
    s += __shfl_xor(s, 1); s += __shfl_xor(s, 2); s += __shfl_xor(s, 4); s += __shfl_xor(s, 8);
    m = fmaxf(m, __shfl_xor(m, 1)); m = fmaxf(m, __shfl_xor(m, 2));
    m = fmaxf(m, __shfl_xor(m, 4)); m = fmaxf(m, __shfl_xor(m, 8));
    if (la == 0) { ps[w][rg*4+j] = s; pm[w][rg*4+j] = m; }
  }
  __syncthreads();
  if (t < 16) {
    float s = ps[0][t] + ps[1][t] + ps[2][t] + ps[3][t];
    float m = fmaxf(fmaxf(pm[0][t], pm[1][t]), fmaxf(pm[2][t], pm[3][t]));
    gpart[(size_t)blockIdx.x*32 + t]      = s;
    gpart[(size_t)blockIdx.x*32 + 16 + t] = m;
  }
  __syncthreads();                        // all gpart stores drained
  if (t == 0) {
    __threadfence();                      // device-visible before signaling
    u32 old = atomicAdd(gcount, 1u);
    lastf = (old == 1023u);
  }
  __syncthreads();
  if (lastf) {
    if (t == 0) __threadfence();          // acquire side
    __syncthreads();
    for (int p = t; p < 512; p += 256) {
      const int b2 = p >> 4, aa = p & 15;
      float s = 0.f, m = 0.f;
      #pragma unroll 4
      for (int blk = 0; blk < 32; ++blk) {
        const float* gp = gpart + (size_t)(b2*32 + blk)*32;
        s += gp[aa]; m = fmaxf(m, gp[16 + aa]);
      }
      float c1 = s * (1.0f/32768.0f) * ca_w1[aa];
      float c2 = m * ca_w1[aa];
      c1 += __shfl_xor(c1, 1); c1 += __shfl_xor(c1, 2); c1 += __shfl_xor(c1, 4); c1 += __shfl_xor(c1, 8);
      c2 += __shfl_xor(c2, 1); c2 += __shfl_xor(c2, 2); c2 += __shfl_xor(c2, 4); c2 += __shfl_xor(c2, 8);
      float g1 = fmaxf(c1, 0.f) + fmaxf(c2, 0.f);
      gate[p] = 1.f / (1.f + __expf(-g1 * ca_w2[aa]));
    }
  }
}

// ---------------- pass B: gate preloaded, fragment-linear W in LDS, nt out stores ----------------
__global__ __launch_bounds__(256, 4) void pass_b(
    const u16* __restrict__ attn, const u16* __restrict__ WvpTr,
    const float* __restrict__ gate, const float* __restrict__ bp,
    float* __restrict__ out)
{
  __shared__ __align__(16) u16 Bs[16384];
  __shared__ float gsh[16];
  const int bx = blockIdx.x;
  const int lg = (bx & 7)*512 + (bx >> 3);
  const int mb = lg >> 2, cb = lg & 3;
  const int b = mb >> 5;
  const int t = threadIdx.x;
  const int w = t >> 6, lane = t & 63;
  const int la = lane & 15, rg = lane >> 4;

  const u16* br0 = attn + (size_t)(mb*128 + w*32 + la)*128 + rg*8;
  const u16* br1 = br0 + 16*128;
  short8 bf0[4], bf1[4];
  #pragma unroll
  for (int kt = 0; kt < 4; ++kt) {
    bf0[kt] = *(const short8*)(br0 + kt*32);
    bf1[kt] = *(const short8*)(br1 + kt*32);
  }

  if (t < 16) gsh[t] = gate[b*16 + t];
  __syncthreads();

  {
    const short8* gs = (const short8*)WvpTr + cb*2048 + t;
    short8* ld = (short8*)Bs + t;
    #pragma unroll
    for (int i = 0; i < 8; ++i) ld[i*256] = gs[i*256];
  }

  float ge[8];
  #pragma unroll
  for (int e = 0; e < 8; ++e) ge[e] = gsh[(rg & 1)*8 + e];
  #pragma unroll
  for (int kt = 0; kt < 4; ++kt) {
    short8 v0 = bf0[kt], v1 = bf1[kt];
    #pragma unroll
    for (int e = 0; e < 8; ++e) {
      v0[e] = (short)f2b(b2f((u16)v0[e]) * ge[e]);
      v1[e] = (short)f2b(b2f((u16)v1[e]) * ge[e]);
    }
    bf0[kt] = v0; bf1[kt] = v1;
  }
  __syncthreads();

  f32x4 acc[2][8];
  #pragma unroll
  for (int i = 0; i < 2; ++i)
    #pragma unroll
    for (int j = 0; j < 8; ++j) acc[i][j] = (f32x4){0.f,0.f,0.f,0.f};

  #pragma unroll
  for (int kt = 0; kt < 4; ++kt) {
    const u16* fb = Bs + (size_t)kt*4096 + lane*8;
    #pragma unroll
    for (int ct = 0; ct < 8; ++ct) {
      short8 af = *(const short8*)(fb + ct*512);
      acc[0][ct] = __builtin_amdgcn_mfma_f32_16x16x32_bf16(af, bf0[kt], acc[0][ct], 0, 0, 0);
      acc[1][ct] = __builtin_amdgcn_mfma_f32_16x16x32_bf16(af, bf1[kt], acc[1][ct], 0, 0, 0);
    }
  }

  #pragma unroll
  for (int nt = 0; nt < 2; ++nt) {
    const size_t row = (size_t)(mb*128 + w*32 + nt*16 + la);
    #pragma unroll
    for (int ct = 0; ct < 8; ++ct) {
      const int col = cb*128 + ct*16 + rg*4;
      const f32x4 bb = *(const f32x4*)(bp + col);
      f32x4 o;
      o[0] = acc[nt][ct][0] + bb[0];
      o[1] = acc[nt][ct][1] + bb[1];
      o[2] = acc[nt][ct][2] + bb[2];
      o[3] = acc[nt][ct][3] + bb[3];
      __builtin_nontemporal_store(o, (f32x4*)(out + row*C_ + col));
    }
  }
}

// ---------------- launch ----------------
extern "C" void kernel_launch(void* const* d_in, const int* in_sizes, int n_in,
                              void* d_out, int out_size, void* d_ws, size_t ws_size,
                              hipStream_t stream)
{
  const float* x       = (const float*)d_in[0];
  const float* Wq      = (const float*)d_in[1];
  const float* bq      = (const float*)d_in[2];
  const float* Wk      = (const float*)d_in[3];
  const float* bk      = (const float*)d_in[4];
  const float* Wv      = (const float*)d_in[5];
  const float* bv      = (const float*)d_in[6];
  const float* Wp      = (const float*)d_in[7];
  const float* bp      = (const float*)d_in[8];
  const float* agent_k = (const float*)d_in[9];
  const float* agent_v = (const float*)d_in[10];
  const float* ca_w1   = (const float*)d_in[11];
  const float* ca_w2   = (const float*)d_in[12];
  float* out = (float*)d_out;

  char* ws = (char*)d_ws;
  u16*   attn   = (u16*)(ws);                          // 33,554,432 B
  float* k2     = (float*)(ws + 33554432);             // 32768
  float* v2     = (float*)(ws + 33587200);             // 32768
  u16*   WqkTr  = (u16*)(ws + 33619968);               // 131072
  float* bqk    = (float*)(ws + 33751040);             // 2048
  u16*   WvpTr  = (u16*)(ws + 33753088);               // 131072
  float* gpart  = (float*)(ws + 33884160);             // 131072
  float* gate   = (float*)(ws + 34015232);             // 2048
  u32*   gcount = (u32*)(ws + 34017280);               // 2048

  // probe scratch
  char* pb = ws + 50331648;
  float* k2p    = (float*)(pb);
  float* v2p    = (float*)(pb + 32768);
  u16*   WqkTrp = (u16*)(pb + 65536);
  float* bqkp   = (float*)(pb + 196608);
  u16*   WvpTrp = (u16*)(pb + 198656);
  u32*   gcntp  = (u32*)(pb + 329728);

  prep_kv<<<128, 256, 0, stream>>>(agent_k, Wk, bk, agent_v, Wv, bv, k2, v2, gcount, 1);
  prep_w<<<640, 256, 0, stream>>>(Wq, bq, k2, Wp, v2, WqkTr, bqk, WvpTr, 1);
  pass_a<<<1024, 256, 0, stream>>>(x, WqkTr, bqk, attn, gpart, ca_w1, ca_w2, gate, gcount);
  pass_b<<<4096, 256, 0, stream>>>(attn, WvpTr, gate, bp, out);

  // ---- diagnostic probes: same code, reps=32 internal loop, scratch outputs ----
  if (ws_size >= 52428800ull) {
    prep_kv<<<128, 256, 0, stream>>>(agent_k, Wk, bk, agent_v, Wv, bv, k2p, v2p, gcntp, 32);
    prep_w<<<640, 256, 0, stream>>>(Wq, bq, k2, Wp, v2, WqkTrp, bqkp, WvpTrp, 32);
  }
}

// Round 13
// 424.273 us; speedup vs baseline: 1.7505x; 1.7505x over previous
//
#include <hip/hip_runtime.h>
#include <hip/hip_cooperative_groups.h>
#include <hip/hip_bf16.h>
#include <stdint.h>

namespace cg = cooperative_groups;

typedef __attribute__((ext_vector_type(8))) short short8;
typedef __attribute__((ext_vector_type(4))) short short4_t;
typedef __attribute__((ext_vector_type(4))) float f32x4;
typedef unsigned short u16;
typedef unsigned int u32;

#define C_ 512

__device__ __forceinline__ u16 f2b(float f){
  u32 u = __float_as_uint(f);
  u += 0x7FFFu + ((u >> 16) & 1u);
  return (u16)(u >> 16);
}
__device__ __forceinline__ float b2f(u16 h){ return __uint_as_float(((u32)h) << 16); }

__device__ __forceinline__ u16 f2b_n(float f){
  __hip_bfloat16 b = __float2bfloat16(f);
  return *reinterpret_cast<u16*>(&b);
}

__device__ __forceinline__ short8 cvt8v(f32x4 lo, f32x4 hi){
  short8 r;
  r[0]=(short)f2b_n(lo[0]); r[1]=(short)f2b_n(lo[1]); r[2]=(short)f2b_n(lo[2]); r[3]=(short)f2b_n(lo[3]);
  r[4]=(short)f2b_n(hi[0]); r[5]=(short)f2b_n(hi[1]); r[6]=(short)f2b_n(hi[2]); r[7]=(short)f2b_n(hi[3]);
  return r;
}

// ---------------- prep: k2/v2 = agent @ W + b ----------------
__global__ __launch_bounds__(256) void prep_kv(
    const float* __restrict__ agent_k, const float* __restrict__ Wk, const float* __restrict__ bk,
    const float* __restrict__ agent_v, const float* __restrict__ Wv, const float* __restrict__ bv,
    float* __restrict__ k2, float* __restrict__ v2, u32* __restrict__ gcount)
{
  const int kv = blockIdx.x >> 6;
  const int c0 = (blockIdx.x & 63) * 8;
  const int t = threadIdx.x;
  const float* ag = kv ? agent_v : agent_k;
  const float* W  = kv ? Wv : Wk;
  const float* bb = kv ? bv : bk;
  float* dst      = kv ? v2 : k2;

  if (blockIdx.x == 0 && t == 0) *gcount = 0u;   // for fallback pass_a last-block gate

  __shared__ float ash[16*512];
  __shared__ float part[32][16][8];

  for (int i = t; i < 8192; i += 256) ash[i] = ag[i];
  __syncthreads();
  const int cl = t & 7, ks = t >> 3;
  float s[16];
  #pragma unroll
  for (int a = 0; a < 16; ++a) s[a] = 0.f;
  #pragma unroll
  for (int i = 0; i < 16; ++i) {
    const int cc = ks*16 + i;
    const float wv = W[(size_t)cc*C_ + c0 + cl];
    #pragma unroll
    for (int a = 0; a < 16; ++a) s[a] += ash[a*512 + cc] * wv;
  }
  #pragma unroll
  for (int a = 0; a < 16; ++a) part[ks][a][cl] = s[a];
  __syncthreads();
  if (t < 128) {
    const int a = t >> 3, c = t & 7;
    float v = bb[c0 + c];
    #pragma unroll
    for (int k = 0; k < 32; ++k) v += part[k][a][c];
    dst[a*C_ + c0 + c] = v;
  }
}

// merged: blocks 0..511 -> WqkTr, blocks 512..639 -> WvpTr
__global__ __launch_bounds__(256) void prep_w(
    const float* __restrict__ Wq, const float* __restrict__ bq, const float* __restrict__ k2,
    const float* __restrict__ Wp, const float* __restrict__ v2,
    u16* __restrict__ WqkTr, float* __restrict__ bqk, u16* __restrict__ WvpTr)
{
  const int bx = blockIdx.x;
  if (bx < 512) {
    const int t = threadIdx.x;
    if (t < 128) {
      const int c = bx, h = t >> 4, a = t & 15;
      const f32x4* wq4 = (const f32x4*)(Wq + (size_t)c*C_ + h*64);
      const f32x4* k24 = (const f32x4*)(k2 + (size_t)a*C_ + h*64);
      float s = 0.f;
      #pragma unroll
      for (int d4 = 0; d4 < 16; ++d4) {
        f32x4 wv = wq4[d4], kv = k24[d4];
        s += wv[0]*kv[0] + wv[1]*kv[1] + wv[2]*kv[2] + wv[3]*kv[3];
      }
      const int kt = c >> 5, rg = (c >> 3) & 3, e = c & 7;
      const int ct = t >> 4, la = t & 15;
      WqkTr[(((kt*8 + ct)*64) + rg*16 + la)*8 + e] = f2b(s * 0.125f);
      if (c == 0){
        const f32x4* bq4 = (const f32x4*)(bq + h*64);
        float sb = 0.f;
        #pragma unroll
        for (int d4 = 0; d4 < 16; ++d4) {
          f32x4 wv = bq4[d4], kv = k24[d4];
          sb += wv[0]*kv[0] + wv[1]*kv[1] + wv[2]*kv[2] + wv[3]*kv[3];
        }
        bqk[t] = sb * 0.125f;
      }
    }
  } else {
    __shared__ float vsh[64];
    const int ha = bx - 512, h = ha >> 4, a = ha & 15;
    if (threadIdx.x < 64) vsh[threadIdx.x] = v2[a*C_ + h*64 + threadIdx.x];
    __syncthreads();
    const int kt = ha >> 5, rg = (ha >> 3) & 3, e = ha & 7;
    for (int co = threadIdx.x; co < C_; co += 256){
      float s = 0.f;
      #pragma unroll
      for (int d = 0; d < 64; ++d) s += vsh[d] * Wp[(size_t)(h*64 + d)*C_ + co];
      const int cb = co >> 7, ct = (co >> 4) & 7, la = co & 15;
      WvpTr[((((cb*4 + kt)*8 + ct)*64) + rg*16 + la)*8 + e] = f2b(s);
    }
  }
}

// =============== fused cooperative: phase A -> grid sync -> gate -> phase B ===============
// grid 1024 x 256, 4 blocks/CU co-resident. Block bx owns rows [bx*128, +128). P never leaves chip.
__global__ __launch_bounds__(256, 4) void fused(
    const float* __restrict__ x, const u16* __restrict__ WqkTr,
    const float* __restrict__ bqk, const u16* __restrict__ WvpTr,
    const float* __restrict__ ca_w1, const float* __restrict__ ca_w2,
    const float* __restrict__ bp, float* __restrict__ out,
    float* __restrict__ gpart, float* __restrict__ gate)
{
  cg::grid_group gg = cg::this_grid();
  __shared__ __align__(16) u16 Bs[16384];          // 32 KB: WqkTr-stage | P frags | WvpTr-stage
  __shared__ float ps[4][16], pm[4][16], gsh[16];

  const int t = threadIdx.x, bx = blockIdx.x;
  const int m0 = bx * 128;
  const int w = t >> 6, lane = t & 63;
  const int la = lane & 15, rg = lane >> 4;

  // ---------- phase A: scores GEMM ----------
  const float* xr0 = x + (size_t)(m0 + w*32 + la)*C_ + rg*8;
  const float* xr1 = xr0 + 16*C_;

  f32x4 acc[2][8];
  #pragma unroll
  for (int i = 0; i < 2; ++i)
    #pragma unroll
    for (int j = 0; j < 8; ++j) acc[i][j] = (f32x4){0.f,0.f,0.f,0.f};

  f32x4 pr0[2][2], pr1[2][2];
#define LOADKT(slot, kt) \
  pr0[slot][0] = __builtin_nontemporal_load((const f32x4*)(xr0 + (kt)*32));     \
  pr0[slot][1] = __builtin_nontemporal_load((const f32x4*)(xr0 + (kt)*32 + 4)); \
  pr1[slot][0] = __builtin_nontemporal_load((const f32x4*)(xr1 + (kt)*32));     \
  pr1[slot][1] = __builtin_nontemporal_load((const f32x4*)(xr1 + (kt)*32 + 4));

  LOADKT(0, 0); LOADKT(1, 1);

  #pragma unroll
  for (int ph = 0; ph < 4; ++ph) {
    __syncthreads();
    {
      const short8* gs = (const short8*)WqkTr + ph*2048 + t;
      short8* ld = (short8*)Bs + t;
      #pragma unroll
      for (int i = 0; i < 8; ++i) ld[i*256] = gs[i*256];
    }
    __syncthreads();
    #pragma unroll
    for (int k4 = 0; k4 < 4; ++k4) {
      const int kt = ph*4 + k4;
      const int sl = kt & 1;
      short8 b0 = cvt8v(pr0[sl][0], pr0[sl][1]);
      short8 b1 = cvt8v(pr1[sl][0], pr1[sl][1]);
      if (kt < 14) { LOADKT(sl, kt + 2); }
      const u16* fb = Bs + (size_t)k4*4096 + lane*8;
      #pragma unroll
      for (int ct = 0; ct < 8; ++ct) {
        short8 af = *(const short8*)(fb + ct*512);
        acc[0][ct] = __builtin_amdgcn_mfma_f32_16x16x32_bf16(af, b0, acc[0][ct], 0, 0, 0);
        acc[1][ct] = __builtin_amdgcn_mfma_f32_16x16x32_bf16(af, b1, acc[1][ct], 0, 0, 0);
      }
    }
  }
#undef LOADKT

  // ---------- softmax over a (in-register) -> packed bf16 P + gating partials ----------
  float psj[4] = {0.f,0.f,0.f,0.f};
  float pmj[4] = {0.f,0.f,0.f,0.f};
  u32 pk[2][8][2];

  #pragma unroll
  for (int nt = 0; nt < 2; ++nt) {
    #pragma unroll
    for (int ct = 0; ct < 8; ++ct) {
      const f32x4 bb = *(const f32x4*)(bqk + ct*16 + rg*4);
      float e0 = __expf(acc[nt][ct][0] + bb[0]);
      float e1 = __expf(acc[nt][ct][1] + bb[1]);
      float e2 = __expf(acc[nt][ct][2] + bb[2]);
      float e3 = __expf(acc[nt][ct][3] + bb[3]);
      float s = e0 + e1 + e2 + e3;
      s += __shfl_xor(s, 16); s += __shfl_xor(s, 32);
      float r = __builtin_amdgcn_rcpf(s);
      float p0 = e0*r, p1 = e1*r, p2 = e2*r, p3 = e3*r;
      psj[0] += p0; psj[1] += p1; psj[2] += p2; psj[3] += p3;
      pmj[0] = fmaxf(pmj[0], p0); pmj[1] = fmaxf(pmj[1], p1);
      pmj[2] = fmaxf(pmj[2], p2); pmj[3] = fmaxf(pmj[3], p3);
      pk[nt][ct][0] = (u32)f2b(p0) | ((u32)f2b(p1) << 16);
      pk[nt][ct][1] = (u32)f2b(p2) | ((u32)f2b(p3) << 16);
    }
  }

  #pragma unroll
  for (int j = 0; j < 4; ++j) {
    float s = psj[j], m = pmj[j];
    s += __shfl_xor(s, 1); s += __shfl_xor(s, 2); s += __shfl_xor(s, 4); s += __shfl_xor(s, 8);
    m = fmaxf(m, __shfl_xor(m, 1)); m = fmaxf(m, __shfl_xor(m, 2));
    m = fmaxf(m, __shfl_xor(m, 4)); m = fmaxf(m, __shfl_xor(m, 8));
    if (la == 0) { ps[w][rg*4+j] = s; pm[w][rg*4+j] = m; }
  }
  __syncthreads();                   // Bs reads done (K-loop), ps/pm visible

  // P -> LDS in phase-B fragment-linear layout (zero-conflict reads later):
  // value (m-row: nt,la ; ha = ct*16 + rg*4 + j) lands at
  //   u16 off = w*4096 + (kt*2+nt)*512 + (rgB*16+la)*8 + eBase
  //   kt = ct>>1, rgB = (ct&1)*2 + (rg>>1), eBase = (rg&1)*4
  #pragma unroll
  for (int nt = 0; nt < 2; ++nt) {
    #pragma unroll
    for (int ct = 0; ct < 8; ++ct) {
      const int off = w*4096 + ((ct>>1)*2 + nt)*512
                    + (((ct&1)*2 + (rg>>1))*16 + la)*8 + (rg&1)*4;
      *(u32*)(Bs + off)     = pk[nt][ct][0];
      *(u32*)(Bs + off + 2) = pk[nt][ct][1];
    }
  }
  if (t < 16) {
    float s = ps[0][t] + ps[1][t] + ps[2][t] + ps[3][t];
    float m = fmaxf(fmaxf(pm[0][t], pm[1][t]), fmaxf(pm[2][t], pm[3][t]));
    gpart[(size_t)bx*32 + t]      = s;
    gpart[(size_t)bx*32 + 16 + t] = m;
  }
  gg.sync();                         // all gpart + P done

  // ---------- gate MLP by block 0 ----------
  if (bx == 0) {
    for (int p = t; p < 512; p += 256) {
      const int b2 = p >> 4, aa = p & 15;
      float s = 0.f, m = 0.f;
      #pragma unroll 4
      for (int blk = 0; blk < 32; ++blk) {
        const float* gp = gpart + (size_t)(b2*32 + blk)*32;
        s += gp[aa]; m = fmaxf(m, gp[16 + aa]);
      }
      float c1 = s * (1.0f/32768.0f) * ca_w1[aa];
      float c2 = m * ca_w1[aa];
      c1 += __shfl_xor(c1, 1); c1 += __shfl_xor(c1, 2); c1 += __shfl_xor(c1, 4); c1 += __shfl_xor(c1, 8);
      c2 += __shfl_xor(c2, 1); c2 += __shfl_xor(c2, 2); c2 += __shfl_xor(c2, 4); c2 += __shfl_xor(c2, 8);
      float g1 = fmaxf(c1, 0.f) + fmaxf(c2, 0.f);
      gate[p] = 1.f / (1.f + __expf(-g1 * ca_w2[aa]));
    }
  }
  gg.sync();                         // gate visible everywhere

  // ---------- phase B: out GEMM, P from LDS, 4 co-tiles ----------
  const int b = bx >> 5;
  if (t < 16) gsh[t] = gate[b*16 + t];
  __syncthreads();

  short8 bf[2][4];
  #pragma unroll
  for (int nt = 0; nt < 2; ++nt)
    #pragma unroll
    for (int kt = 0; kt < 4; ++kt)
      bf[nt][kt] = *(const short8*)(Bs + w*4096 + (kt*2+nt)*512 + (rg*16+la)*8);

  float ge[8];
  #pragma unroll
  for (int e = 0; e < 8; ++e) ge[e] = gsh[(rg & 1)*8 + e];
  #pragma unroll
  for (int nt = 0; nt < 2; ++nt)
    #pragma unroll
    for (int kt = 0; kt < 4; ++kt) {
      short8 v = bf[nt][kt];
      #pragma unroll
      for (int e = 0; e < 8; ++e) v[e] = (short)f2b(b2f((u16)v[e]) * ge[e]);
      bf[nt][kt] = v;
    }
  __syncthreads();                   // P reads retired; Bs free for staging

  #pragma unroll 1
  for (int cb = 0; cb < 4; ++cb) {
    {
      const short8* gs = (const short8*)WvpTr + cb*2048 + t;
      short8* ld = (short8*)Bs + t;
      #pragma unroll
      for (int i = 0; i < 8; ++i) ld[i*256] = gs[i*256];
    }
    __syncthreads();

    f32x4 acc2[2][8];
    #pragma unroll
    for (int i = 0; i < 2; ++i)
      #pragma unroll
      for (int j = 0; j < 8; ++j) acc2[i][j] = (f32x4){0.f,0.f,0.f,0.f};

    #pragma unroll
    for (int kt = 0; kt < 4; ++kt) {
      const u16* fb = Bs + (size_t)kt*4096 + lane*8;
      #pragma unroll
      for (int ct = 0; ct < 8; ++ct) {
        short8 af = *(const short8*)(fb + ct*512);
        acc2[0][ct] = __builtin_amdgcn_mfma_f32_16x16x32_bf16(af, bf[0][kt], acc2[0][ct], 0, 0, 0);
        acc2[1][ct] = __builtin_amdgcn_mfma_f32_16x16x32_bf16(af, bf[1][kt], acc2[1][ct], 0, 0, 0);
      }
    }
    __syncthreads();                 // Bs reads done before next cb staging

    #pragma unroll
    for (int nt = 0; nt < 2; ++nt) {
      const size_t row = (size_t)(m0 + w*32 + nt*16 + la);
      #pragma unroll
      for (int ct = 0; ct < 8; ++ct) {
        const int col = cb*128 + ct*16 + rg*4;
        const f32x4 bb = *(const f32x4*)(bp + col);
        f32x4 o;
        o[0] = acc2[nt][ct][0] + bb[0];
        o[1] = acc2[nt][ct][1] + bb[1];
        o[2] = acc2[nt][ct][2] + bb[2];
        o[3] = acc2[nt][ct][3] + bb[3];
        __builtin_nontemporal_store(o, (f32x4*)(out + row*C_ + col));
      }
    }
  }
}

// =============== fallback: r12-validated two-pass path ===============
__global__ __launch_bounds__(256, 4) void pass_a(
    const float* __restrict__ x, const u16* __restrict__ WqkTr,
    const float* __restrict__ bqk, u16* __restrict__ attn,
    float* __restrict__ gpart, const float* __restrict__ ca_w1,
    const float* __restrict__ ca_w2, float* __restrict__ gate, u32* __restrict__ gcount)
{
  __shared__ __align__(16) u16 Bs[16384];
  __shared__ float ps[4][16], pm[4][16];
  __shared__ int lastf;

  const int t = threadIdx.x;
  const int m0 = blockIdx.x * 128;
  const int w = t >> 6, lane = t & 63;
  const int la = lane & 15, rg = lane >> 4;

  const float* xr0 = x + (size_t)(m0 + w*32 + la)*C_ + rg*8;
  const float* xr1 = xr0 + 16*C_;

  f32x4 acc[2][8];
  #pragma unroll
  for (int i = 0; i < 2; ++i)
    #pragma unroll
    for (int j = 0; j < 8; ++j) acc[i][j] = (f32x4){0.f,0.f,0.f,0.f};

  f32x4 pr0[2][2], pr1[2][2];
#define LOADKT(slot, kt) \
  pr0[slot][0] = __builtin_nontemporal_load((const f32x4*)(xr0 + (kt)*32));     \
  pr0[slot][1] = __builtin_nontemporal_load((const f32x4*)(xr0 + (kt)*32 + 4)); \
  pr1[slot][0] = __builtin_nontemporal_load((const f32x4*)(xr1 + (kt)*32));     \
  pr1[slot][1] = __builtin_nontemporal_load((const f32x4*)(xr1 + (kt)*32 + 4));

  LOADKT(0, 0); LOADKT(1, 1);

  #pragma unroll
  for (int ph = 0; ph < 4; ++ph) {
    __syncthreads();
    {
      const short8* gs = (const short8*)WqkTr + ph*2048 + t;
      short8* ld = (short8*)Bs + t;
      #pragma unroll
      for (int i = 0; i < 8; ++i) ld[i*256] = gs[i*256];
    }
    __syncthreads();
    #pragma unroll
    for (int k4 = 0; k4 < 4; ++k4) {
      const int kt = ph*4 + k4;
      const int sl = kt & 1;
      short8 b0 = cvt8v(pr0[sl][0], pr0[sl][1]);
      short8 b1 = cvt8v(pr1[sl][0], pr1[sl][1]);
      if (kt < 14) { LOADKT(sl, kt + 2); }
      const u16* fb = Bs + (size_t)k4*4096 + lane*8;
      #pragma unroll
      for (int ct = 0; ct < 8; ++ct) {
        short8 af = *(const short8*)(fb + ct*512);
        acc[0][ct] = __builtin_amdgcn_mfma_f32_16x16x32_bf16(af, b0, acc[0][ct], 0, 0, 0);
        acc[1][ct] = __builtin_amdgcn_mfma_f32_16x16x32_bf16(af, b1, acc[1][ct], 0, 0, 0);
      }
    }
  }
#undef LOADKT

  float psj[4] = {0.f,0.f,0.f,0.f};
  float pmj[4] = {0.f,0.f,0.f,0.f};

  #pragma unroll
  for (int nt = 0; nt < 2; ++nt) {
    const int row = m0 + w*32 + nt*16 + la;
    #pragma unroll
    for (int ct = 0; ct < 8; ++ct) {
      const f32x4 bb = *(const f32x4*)(bqk + ct*16 + rg*4);
      float e0 = __expf(acc[nt][ct][0] + bb[0]);
      float e1 = __expf(acc[nt][ct][1] + bb[1]);
      float e2 = __expf(acc[nt][ct][2] + bb[2]);
      float e3 = __expf(acc[nt][ct][3] + bb[3]);
      float s = e0 + e1 + e2 + e3;
      s += __shfl_xor(s, 16); s += __shfl_xor(s, 32);
      float r = __builtin_amdgcn_rcpf(s);
      float p0 = e0*r, p1 = e1*r, p2 = e2*r, p3 = e3*r;
      psj[0] += p0; psj[1] += p1; psj[2] += p2; psj[3] += p3;
      pmj[0] = fmaxf(pmj[0], p0); pmj[1] = fmaxf(pmj[1], p1);
      pmj[2] = fmaxf(pmj[2], p2); pmj[3] = fmaxf(pmj[3], p3);
      short4_t st;
      st[0]=(short)f2b(p0); st[1]=(short)f2b(p1); st[2]=(short)f2b(p2); st[3]=(short)f2b(p3);
      *(short4_t*)(attn + (size_t)row*128 + ct*16 + rg*4) = st;
    }
  }

  #pragma unroll
  for (int j = 0; j < 4; ++j) {
    float s = psj[j], m = pmj[j];
    s += __shfl_xor(s, 1); s += __shfl_xor(s, 2); s += __shfl_xor(s, 4); s += __shfl_xor(s, 8);
    m = fmaxf(m, __shfl_xor(m, 1)); m = fmaxf(m, __shfl_xor(m, 2));
    m = fmaxf(m, __shfl_xor(m, 4)); m = fmaxf(m, __shfl_xor(m, 8));
    if (la == 0) { ps[w][rg*4+j] = s; pm[w][rg*4+j] = m; }
  }
  __syncthreads();
  if (t < 16) {
    float s = ps[0][t] + ps[1][t] + ps[2][t] + ps[3][t];
    float m = fmaxf(fmaxf(pm[0][t], pm[1][t]), fmaxf(pm[2][t], pm[3][t]));
    gpart[(size_t)blockIdx.x*32 + t]      = s;
    gpart[(size_t)blockIdx.x*32 + 16 + t] = m;
  }
  __syncthreads();
  if (t == 0) {
    __threadfence();
    u32 old = atomicAdd(gcount, 1u);
    lastf = (old == 1023u);
  }
  __syncthreads();
  if (lastf) {
    if (t == 0) __threadfence();
    __syncthreads();
    for (int p = t; p < 512; p += 256) {
      const int b2 = p >> 4, aa = p & 15;
      float s = 0.f, m = 0.f;
      #pragma unroll 4
      for (int blk = 0; blk < 32; ++blk) {
        const float* gp = gpart + (size_t)(b2*32 + blk)*32;
        s += gp[aa]; m = fmaxf(m, gp[16 + aa]);
      }
      float c1 = s * (1.0f/32768.0f) * ca_w1[aa];
      float c2 = m * ca_w1[aa];
      c1 += __shfl_xor(c1, 1); c1 += __shfl_xor(c1, 2); c1 += __shfl_xor(c1, 4); c1 += __shfl_xor(c1, 8);
      c2 += __shfl_xor(c2, 1); c2 += __shfl_xor(c2, 2); c2 += __shfl_xor(c2, 4); c2 += __shfl_xor(c2, 8);
      float g1 = fmaxf(c1, 0.f) + fmaxf(c2, 0.f);
      gate[p] = 1.f / (1.f + __expf(-g1 * ca_w2[aa]));
    }
  }
}

__global__ __launch_bounds__(256, 4) void pass_b(
    const u16* __restrict__ attn, const u16* __restrict__ WvpTr,
    const float* __restrict__ gate, const float* __restrict__ bp,
    float* __restrict__ out)
{
  __shared__ __align__(16) u16 Bs[16384];
  __shared__ float gsh[16];
  const int bx = blockIdx.x;
  const int lg = (bx & 7)*512 + (bx >> 3);
  const int mb = lg >> 2, cb = lg & 3;
  const int b = mb >> 5;
  const int t = threadIdx.x;
  const int w = t >> 6, lane = t & 63;
  const int la = lane & 15, rg = lane >> 4;

  const u16* br0 = attn + (size_t)(mb*128 + w*32 + la)*128 + rg*8;
  const u16* br1 = br0 + 16*128;
  short8 bf0[4], bf1[4];
  #pragma unroll
  for (int kt = 0; kt < 4; ++kt) {
    bf0[kt] = *(const short8*)(br0 + kt*32);
    bf1[kt] = *(const short8*)(br1 + kt*32);
  }

  if (t < 16) gsh[t] = gate[b*16 + t];
  __syncthreads();

  {
    const short8* gs = (const short8*)WvpTr + cb*2048 + t;
    short8* ld = (short8*)Bs + t;
    #pragma unroll
    for (int i = 0; i < 8; ++i) ld[i*256] = gs[i*256];
  }

  float ge[8];
  #pragma unroll
  for (int e = 0; e < 8; ++e) ge[e] = gsh[(rg & 1)*8 + e];
  #pragma unroll
  for (int kt = 0; kt < 4; ++kt) {
    short8 v0 = bf0[kt], v1 = bf1[kt];
    #pragma unroll
    for (int e = 0; e < 8; ++e) {
      v0[e] = (short)f2b(b2f((u16)v0[e]) * ge[e]);
      v1[e] = (short)f2b(b2f((u16)v1[e]) * ge[e]);
    }
    bf0[kt] = v0; bf1[kt] = v1;
  }
  __syncthreads();

  f32x4 acc[2][8];
  #pragma unroll
  for (int i = 0; i < 2; ++i)
    #pragma unroll
    for (int j = 0; j < 8; ++j) acc[i][j] = (f32x4){0.f,0.f,0.f,0.f};

  #pragma unroll
  for (int kt = 0; kt < 4; ++kt) {
    const u16* fb = Bs + (size_t)kt*4096 + lane*8;
    #pragma unroll
    for (int ct = 0; ct < 8; ++ct) {
      short8 af = *(const short8*)(fb + ct*512);
      acc[0][ct] = __builtin_amdgcn_mfma_f32_16x16x32_bf16(af, bf0[kt], acc[0][ct], 0, 0, 0);
      acc[1][ct] = __builtin_amdgcn_mfma_f32_16x16x32_bf16(af, bf1[kt], acc[1][ct], 0, 0, 0);
    }
  }

  #pragma unroll
  for (int nt = 0; nt < 2; ++nt) {
    const size_t row = (size_t)(mb*128 + w*32 + nt*16 + la);
    #pragma unroll
    for (int ct = 0; ct < 8; ++ct) {
      const int col = cb*128 + ct*16 + rg*4;
      const f32x4 bb = *(const f32x4*)(bp + col);
      f32x4 o;
      o[0] = acc[nt][ct][0] + bb[0];
      o[1] = acc[nt][ct][1] + bb[1];
      o[2] = acc[nt][ct][2] + bb[2];
      o[3] = acc[nt][ct][3] + bb[3];
      __builtin_nontemporal_store(o, (f32x4*)(out + row*C_ + col));
    }
  }
}

// ---------------- launch ----------------
extern "C" void kernel_launch(void* const* d_in, const int* in_sizes, int n_in,
                              void* d_out, int out_size, void* d_ws, size_t ws_size,
                              hipStream_t stream)
{
  const float* x       = (const float*)d_in[0];
  const float* Wq      = (const float*)d_in[1];
  const float* bq      = (const float*)d_in[2];
  const float* Wk      = (const float*)d_in[3];
  const float* bk      = (const float*)d_in[4];
  const float* Wv      = (const float*)d_in[5];
  const float* bv      = (const float*)d_in[6];
  const float* Wp      = (const float*)d_in[7];
  const float* bp      = (const float*)d_in[8];
  const float* agent_k = (const float*)d_in[9];
  const float* agent_v = (const float*)d_in[10];
  const float* ca_w1   = (const float*)d_in[11];
  const float* ca_w2   = (const float*)d_in[12];
  float* out = (float*)d_out;

  char* ws = (char*)d_ws;
  u16*   attn   = (u16*)(ws);                          // 33,554,432 B (fallback only)
  float* k2     = (float*)(ws + 33554432);             // 32768
  float* v2     = (float*)(ws + 33587200);             // 32768
  u16*   WqkTr  = (u16*)(ws + 33619968);               // 131072
  float* bqk    = (float*)(ws + 33751040);             // 2048
  u16*   WvpTr  = (u16*)(ws + 33753088);               // 131072
  float* gpart  = (float*)(ws + 33884160);             // 131072
  float* gate   = (float*)(ws + 34015232);             // 2048
  u32*   gcount = (u32*)(ws + 34017280);               // 2048

  prep_kv<<<128, 256, 0, stream>>>(agent_k, Wk, bk, agent_v, Wv, bv, k2, v2, gcount);
  prep_w<<<640, 256, 0, stream>>>(Wq, bq, k2, Wp, v2, WqkTr, bqk, WvpTr);

  void* ka[10];
  ka[0] = (void*)&x;     ka[1] = (void*)&WqkTr; ka[2] = (void*)&bqk;
  ka[3] = (void*)&WvpTr; ka[4] = (void*)&ca_w1; ka[5] = (void*)&ca_w2;
  ka[6] = (void*)&bp;    ka[7] = (void*)&out;   ka[8] = (void*)&gpart;
  ka[9] = (void*)&gate;

  hipError_t err = hipLaunchCooperativeKernel(reinterpret_cast<void*>(fused),
                                              dim3(1024), dim3(256), ka, 0u, stream);
  if (err != hipSuccess) {
    (void)hipGetLastError();
    pass_a<<<1024, 256, 0, stream>>>(x, WqkTr, bqk, attn, gpart, ca_w1, ca_w2, gate, gcount);
    pass_b<<<4096, 256, 0, stream>>>(attn, WvpTr, gate, bp, out);
  }
}

// Round 14
// 279.116 us; speedup vs baseline: 2.6609x; 1.5201x over previous
//
#include <hip/hip_runtime.h>
#include <hip/hip_bf16.h>
#include <stdint.h>

typedef __attribute__((ext_vector_type(8))) short short8;
typedef __attribute__((ext_vector_type(4))) short short4_t;
typedef __attribute__((ext_vector_type(4))) float f32x4;
typedef unsigned short u16;
typedef unsigned int u32;

#define C_ 512

__device__ __forceinline__ u16 f2b(float f){
  u32 u = __float_as_uint(f);
  u += 0x7FFFu + ((u >> 16) & 1u);
  return (u16)(u >> 16);
}
__device__ __forceinline__ float b2f(u16 h){ return __uint_as_float(((u32)h) << 16); }

__device__ __forceinline__ u16 f2b_n(float f){
  __hip_bfloat16 b = __float2bfloat16(f);
  return *reinterpret_cast<u16*>(&b);
}

__device__ __forceinline__ short8 cvt8v(f32x4 lo, f32x4 hi){
  short8 r;
  r[0]=(short)f2b_n(lo[0]); r[1]=(short)f2b_n(lo[1]); r[2]=(short)f2b_n(lo[2]); r[3]=(short)f2b_n(lo[3]);
  r[4]=(short)f2b_n(hi[0]); r[5]=(short)f2b_n(hi[1]); r[6]=(short)f2b_n(hi[2]); r[7]=(short)f2b_n(hi[3]);
  return r;
}

// ---------------- prep: k2/v2 = agent @ W + b ----------------
__global__ __launch_bounds__(256) void prep_kv(
    const float* __restrict__ agent_k, const float* __restrict__ Wk, const float* __restrict__ bk,
    const float* __restrict__ agent_v, const float* __restrict__ Wv, const float* __restrict__ bv,
    float* __restrict__ k2, float* __restrict__ v2, u32* __restrict__ gcount)
{
  const int kv = blockIdx.x >> 6;
  const int c0 = (blockIdx.x & 63) * 8;
  const int t = threadIdx.x;
  const float* ag = kv ? agent_v : agent_k;
  const float* W  = kv ? Wv : Wk;
  const float* bb = kv ? bv : bk;
  float* dst      = kv ? v2 : k2;

  if (blockIdx.x == 0 && t == 0) *gcount = 0u;   // reset for pass_a's last-block gate

  __shared__ float ash[16*512];
  __shared__ float part[32][16][8];

  for (int i = t; i < 8192; i += 256) ash[i] = ag[i];
  __syncthreads();
  const int cl = t & 7, ks = t >> 3;
  float s[16];
  #pragma unroll
  for (int a = 0; a < 16; ++a) s[a] = 0.f;
  #pragma unroll
  for (int i = 0; i < 16; ++i) {
    const int cc = ks*16 + i;
    const float wv = W[(size_t)cc*C_ + c0 + cl];
    #pragma unroll
    for (int a = 0; a < 16; ++a) s[a] += ash[a*512 + cc] * wv;
  }
  #pragma unroll
  for (int a = 0; a < 16; ++a) part[ks][a][cl] = s[a];
  __syncthreads();
  if (t < 128) {
    const int a = t >> 3, c = t & 7;
    float v = bb[c0 + c];
    #pragma unroll
    for (int k = 0; k < 32; ++k) v += part[k][a][c];
    dst[a*C_ + c0 + c] = v;
  }
}

// merged: blocks 0..511 -> WqkTr, blocks 512..639 -> WvpTr
__global__ __launch_bounds__(256) void prep_w(
    const float* __restrict__ Wq, const float* __restrict__ bq, const float* __restrict__ k2,
    const float* __restrict__ Wp, const float* __restrict__ v2,
    u16* __restrict__ WqkTr, float* __restrict__ bqk, u16* __restrict__ WvpTr)
{
  const int bx = blockIdx.x;
  if (bx < 512) {
    const int t = threadIdx.x;
    if (t < 128) {
      const int c = bx, h = t >> 4, a = t & 15;
      const f32x4* wq4 = (const f32x4*)(Wq + (size_t)c*C_ + h*64);
      const f32x4* k24 = (const f32x4*)(k2 + (size_t)a*C_ + h*64);
      float s = 0.f;
      #pragma unroll
      for (int d4 = 0; d4 < 16; ++d4) {
        f32x4 wv = wq4[d4], kv = k24[d4];
        s += wv[0]*kv[0] + wv[1]*kv[1] + wv[2]*kv[2] + wv[3]*kv[3];
      }
      const int kt = c >> 5, rg = (c >> 3) & 3, e = c & 7;
      const int ct = t >> 4, la = t & 15;
      WqkTr[(((kt*8 + ct)*64) + rg*16 + la)*8 + e] = f2b(s * 0.125f);
      if (c == 0){
        const f32x4* bq4 = (const f32x4*)(bq + h*64);
        float sb = 0.f;
        #pragma unroll
        for (int d4 = 0; d4 < 16; ++d4) {
          f32x4 wv = bq4[d4], kv = k24[d4];
          sb += wv[0]*kv[0] + wv[1]*kv[1] + wv[2]*kv[2] + wv[3]*kv[3];
        }
        bqk[t] = sb * 0.125f;
      }
    }
  } else {
    __shared__ float vsh[64];
    const int ha = bx - 512, h = ha >> 4, a = ha & 15;
    if (threadIdx.x < 64) vsh[threadIdx.x] = v2[a*C_ + h*64 + threadIdx.x];
    __syncthreads();
    const int kt = ha >> 5, rg = (ha >> 3) & 3, e = ha & 7;
    for (int co = threadIdx.x; co < C_; co += 256){
      float s = 0.f;
      #pragma unroll
      for (int d = 0; d < 64; ++d) s += vsh[d] * Wp[(size_t)(h*64 + d)*C_ + co];
      const int cb = co >> 7, ct = (co >> 4) & 7, la = co & 15;
      WvpTr[((((cb*4 + kt)*8 + ct)*64) + rg*16 + la)*8 + e] = f2b(s);
    }
  }
}

// ---------------- pass A: fragment-linear B in LDS, nt x-loads, last-block gate ----------------
__global__ __launch_bounds__(256, 4) void pass_a(
    const float* __restrict__ x, const u16* __restrict__ WqkTr,
    const float* __restrict__ bqk, u16* __restrict__ attn,
    float* __restrict__ gpart, const float* __restrict__ ca_w1,
    const float* __restrict__ ca_w2, float* __restrict__ gate, u32* __restrict__ gcount)
{
  __shared__ __align__(16) u16 Bs[16384];
  __shared__ float ps[4][16], pm[4][16];
  __shared__ int lastf;

  const int t = threadIdx.x;
  const int m0 = blockIdx.x * 128;
  const int w = t >> 6, lane = t & 63;
  const int la = lane & 15, rg = lane >> 4;

  const float* xr0 = x + (size_t)(m0 + w*32 + la)*C_ + rg*8;
  const float* xr1 = xr0 + 16*C_;

  f32x4 acc[2][8];
  #pragma unroll
  for (int i = 0; i < 2; ++i)
    #pragma unroll
    for (int j = 0; j < 8; ++j) acc[i][j] = (f32x4){0.f,0.f,0.f,0.f};

  f32x4 pr0[2][2], pr1[2][2];
#define LOADKT(slot, kt) \
  pr0[slot][0] = __builtin_nontemporal_load((const f32x4*)(xr0 + (kt)*32));     \
  pr0[slot][1] = __builtin_nontemporal_load((const f32x4*)(xr0 + (kt)*32 + 4)); \
  pr1[slot][0] = __builtin_nontemporal_load((const f32x4*)(xr1 + (kt)*32));     \
  pr1[slot][1] = __builtin_nontemporal_load((const f32x4*)(xr1 + (kt)*32 + 4));

  LOADKT(0, 0); LOADKT(1, 1);

  #pragma unroll
  for (int ph = 0; ph < 4; ++ph) {
    __syncthreads();
    {
      const short8* gs = (const short8*)WqkTr + ph*2048 + t;
      short8* ld = (short8*)Bs + t;
      #pragma unroll
      for (int i = 0; i < 8; ++i) ld[i*256] = gs[i*256];
    }
    __syncthreads();
    #pragma unroll
    for (int k4 = 0; k4 < 4; ++k4) {
      const int kt = ph*4 + k4;
      const int sl = kt & 1;
      short8 b0 = cvt8v(pr0[sl][0], pr0[sl][1]);
      short8 b1 = cvt8v(pr1[sl][0], pr1[sl][1]);
      if (kt < 14) { LOADKT(sl, kt + 2); }
      const u16* fb = Bs + (size_t)k4*4096 + lane*8;
      #pragma unroll
      for (int ct = 0; ct < 8; ++ct) {
        short8 af = *(const short8*)(fb + ct*512);
        acc[0][ct] = __builtin_amdgcn_mfma_f32_16x16x32_bf16(af, b0, acc[0][ct], 0, 0, 0);
        acc[1][ct] = __builtin_amdgcn_mfma_f32_16x16x32_bf16(af, b1, acc[1][ct], 0, 0, 0);
      }
    }
  }
#undef LOADKT

  float psj[4] = {0.f,0.f,0.f,0.f};
  float pmj[4] = {0.f,0.f,0.f,0.f};

  #pragma unroll
  for (int nt = 0; nt < 2; ++nt) {
    const int row = m0 + w*32 + nt*16 + la;
    #pragma unroll
    for (int ct = 0; ct < 8; ++ct) {
      const f32x4 bb = *(const f32x4*)(bqk + ct*16 + rg*4);
      float e0 = __expf(acc[nt][ct][0] + bb[0]);
      float e1 = __expf(acc[nt][ct][1] + bb[1]);
      float e2 = __expf(acc[nt][ct][2] + bb[2]);
      float e3 = __expf(acc[nt][ct][3] + bb[3]);
      float s = e0 + e1 + e2 + e3;
      s += __shfl_xor(s, 16); s += __shfl_xor(s, 32);
      float r = __builtin_amdgcn_rcpf(s);
      float p0 = e0*r, p1 = e1*r, p2 = e2*r, p3 = e3*r;
      psj[0] += p0; psj[1] += p1; psj[2] += p2; psj[3] += p3;
      pmj[0] = fmaxf(pmj[0], p0); pmj[1] = fmaxf(pmj[1], p1);
      pmj[2] = fmaxf(pmj[2], p2); pmj[3] = fmaxf(pmj[3], p3);
      short4_t st;
      st[0]=(short)f2b(p0); st[1]=(short)f2b(p1); st[2]=(short)f2b(p2); st[3]=(short)f2b(p3);
      *(short4_t*)(attn + (size_t)row*128 + ct*16 + rg*4) = st;
    }
  }

  #pragma unroll
  for (int j = 0; j < 4; ++j) {
    float s = psj[j], m = pmj[j];
    s += __shfl_xor(s, 1); s += __shfl_xor(s, 2); s += __shfl_xor(s, 4); s += __shfl_xor(s, 8);
    m = fmaxf(m, __shfl_xor(m, 1)); m = fmaxf(m, __shfl_xor(m, 2));
    m = fmaxf(m, __shfl_xor(m, 4)); m = fmaxf(m, __shfl_xor(m, 8));
    if (la == 0) { ps[w][rg*4+j] = s; pm[w][rg*4+j] = m; }
  }
  __syncthreads();
  if (t < 16) {
    float s = ps[0][t] + ps[1][t] + ps[2][t] + ps[3][t];
    float m = fmaxf(fmaxf(pm[0][t], pm[1][t]), fmaxf(pm[2][t], pm[3][t]));
    gpart[(size_t)blockIdx.x*32 + t]      = s;
    gpart[(size_t)blockIdx.x*32 + 16 + t] = m;
  }
  __syncthreads();
  if (t == 0) {
    __threadfence();
    u32 old = atomicAdd(gcount, 1u);
    lastf = (old == 1023u);
  }
  __syncthreads();
  if (lastf) {
    if (t == 0) __threadfence();
    __syncthreads();
    for (int p = t; p < 512; p += 256) {
      const int b2 = p >> 4, aa = p & 15;
      float s = 0.f, m = 0.f;
      #pragma unroll 4
      for (int blk = 0; blk < 32; ++blk) {
        const float* gp = gpart + (size_t)(b2*32 + blk)*32;
        s += gp[aa]; m = fmaxf(m, gp[16 + aa]);
      }
      float c1 = s * (1.0f/32768.0f) * ca_w1[aa];
      float c2 = m * ca_w1[aa];
      c1 += __shfl_xor(c1, 1); c1 += __shfl_xor(c1, 2); c1 += __shfl_xor(c1, 4); c1 += __shfl_xor(c1, 8);
      c2 += __shfl_xor(c2, 1); c2 += __shfl_xor(c2, 2); c2 += __shfl_xor(c2, 4); c2 += __shfl_xor(c2, 8);
      float g1 = fmaxf(c1, 0.f) + fmaxf(c2, 0.f);
      gate[p] = 1.f / (1.f + __expf(-g1 * ca_w2[aa]));
    }
  }
}

// ---------------- pass B: 1024 blocks, attn read ONCE, 4 cb-tiles per block ----------------
__global__ __launch_bounds__(256, 4) void pass_b(
    const u16* __restrict__ attn, const u16* __restrict__ WvpTr,
    const float* __restrict__ gate, const float* __restrict__ bp,
    float* __restrict__ out)
{
  __shared__ __align__(16) u16 Bs[16384];
  __shared__ float gsh[16];
  const int bx = blockIdx.x;
  const int mb = (bx & 7)*128 + (bx >> 3);   // XCD swizzle over 1024
  const int b = mb >> 5;
  const int t = threadIdx.x;
  const int w = t >> 6, lane = t & 63;
  const int la = lane & 15, rg = lane >> 4;

  // attn fragments once (read-once -> nt loads)
  const u16* br0 = attn + (size_t)(mb*128 + w*32 + la)*128 + rg*8;
  const u16* br1 = br0 + 16*128;
  short8 bf0[4], bf1[4];
  #pragma unroll
  for (int kt = 0; kt < 4; ++kt) {
    bf0[kt] = __builtin_nontemporal_load((const short8*)(br0 + kt*32));
    bf1[kt] = __builtin_nontemporal_load((const short8*)(br1 + kt*32));
  }

  if (t < 16) gsh[t] = gate[b*16 + t];
  __syncthreads();

  // gate folded into P-fragments once: k&15 = (rg&1)*8 + e
  float ge[8];
  #pragma unroll
  for (int e = 0; e < 8; ++e) ge[e] = gsh[(rg & 1)*8 + e];
  #pragma unroll
  for (int kt = 0; kt < 4; ++kt) {
    short8 v0 = bf0[kt], v1 = bf1[kt];
    #pragma unroll
    for (int e = 0; e < 8; ++e) {
      v0[e] = (short)f2b(b2f((u16)v0[e]) * ge[e]);
      v1[e] = (short)f2b(b2f((u16)v1[e]) * ge[e]);
    }
    bf0[kt] = v0; bf1[kt] = v1;
  }

  #pragma unroll 1
  for (int cb = 0; cb < 4; ++cb) {
    if (cb) __syncthreads();               // prior cb's LDS reads complete
    {
      const short8* gs = (const short8*)WvpTr + cb*2048 + t;
      short8* ld = (short8*)Bs + t;
      #pragma unroll
      for (int i = 0; i < 8; ++i) ld[i*256] = gs[i*256];
    }
    __syncthreads();

    f32x4 acc[2][8];
    #pragma unroll
    for (int i = 0; i < 2; ++i)
      #pragma unroll
      for (int j = 0; j < 8; ++j) acc[i][j] = (f32x4){0.f,0.f,0.f,0.f};

    #pragma unroll
    for (int kt = 0; kt < 4; ++kt) {
      const u16* fb = Bs + (size_t)kt*4096 + lane*8;
      #pragma unroll
      for (int ct = 0; ct < 8; ++ct) {
        short8 af = *(const short8*)(fb + ct*512);
        acc[0][ct] = __builtin_amdgcn_mfma_f32_16x16x32_bf16(af, bf0[kt], acc[0][ct], 0, 0, 0);
        acc[1][ct] = __builtin_amdgcn_mfma_f32_16x16x32_bf16(af, bf1[kt], acc[1][ct], 0, 0, 0);
      }
    }

    #pragma unroll
    for (int nt = 0; nt < 2; ++nt) {
      const size_t row = (size_t)(mb*128 + w*32 + nt*16 + la);
      #pragma unroll
      for (int ct = 0; ct < 8; ++ct) {
        const int col = cb*128 + ct*16 + rg*4;
        const f32x4 bb = *(const f32x4*)(bp + col);
        f32x4 o;
        o[0] = acc[nt][ct][0] + bb[0];
        o[1] = acc[nt][ct][1] + bb[1];
        o[2] = acc[nt][ct][2] + bb[2];
        o[3] = acc[nt][ct][3] + bb[3];
        __builtin_nontemporal_store(o, (f32x4*)(out + row*C_ + col));
      }
    }
  }
}

// ---------------- launch ----------------
extern "C" void kernel_launch(void* const* d_in, const int* in_sizes, int n_in,
                              void* d_out, int out_size, void* d_ws, size_t ws_size,
                              hipStream_t stream)
{
  const float* x       = (const float*)d_in[0];
  const float* Wq      = (const float*)d_in[1];
  const float* bq      = (const float*)d_in[2];
  const float* Wk      = (const float*)d_in[3];
  const float* bk      = (const float*)d_in[4];
  const float* Wv      = (const float*)d_in[5];
  const float* bv      = (const float*)d_in[6];
  const float* Wp      = (const float*)d_in[7];
  const float* bp      = (const float*)d_in[8];
  const float* agent_k = (const float*)d_in[9];
  const float* agent_v = (const float*)d_in[10];
  const float* ca_w1   = (const float*)d_in[11];
  const float* ca_w2   = (const float*)d_in[12];
  float* out = (float*)d_out;

  char* ws = (char*)d_ws;
  u16*   attn   = (u16*)(ws);                          // 33,554,432 B
  float* k2     = (float*)(ws + 33554432);             // 32768
  float* v2     = (float*)(ws + 33587200);             // 32768
  u16*   WqkTr  = (u16*)(ws + 33619968);               // 131072
  float* bqk    = (float*)(ws + 33751040);             // 2048
  u16*   WvpTr  = (u16*)(ws + 33753088);               // 131072
  float* gpart  = (float*)(ws + 33884160);             // 131072
  float* gate   = (float*)(ws + 34015232);             // 2048
  u32*   gcount = (u32*)(ws + 34017280);               // 2048

  prep_kv<<<128, 256, 0, stream>>>(agent_k, Wk, bk, agent_v, Wv, bv, k2, v2, gcount);
  prep_w<<<640, 256, 0, stream>>>(Wq, bq, k2, Wp, v2, WqkTr, bqk, WvpTr);
  pass_a<<<1024, 256, 0, stream>>>(x, WqkTr, bqk, attn, gpart, ca_w1, ca_w2, gate, gcount);
  pass_b<<<1024, 256, 0, stream>>>(attn, WvpTr, gate, bp, out);
}

// Round 15
// 232.428 us; speedup vs baseline: 3.1953x; 1.2009x over previous
//
#include <hip/hip_runtime.h>
#include <hip/hip_bf16.h>
#include <stdint.h>

typedef __attribute__((ext_vector_type(8))) short short8;
typedef __attribute__((ext_vector_type(4))) short short4_t;
typedef __attribute__((ext_vector_type(4))) float f32x4;
typedef unsigned short u16;
typedef unsigned int u32;

#define C_ 512

__device__ __forceinline__ u16 f2b(float f){
  u32 u = __float_as_uint(f);
  u += 0x7FFFu + ((u >> 16) & 1u);
  return (u16)(u >> 16);
}
__device__ __forceinline__ float b2f(u16 h){ return __uint_as_float(((u32)h) << 16); }

__device__ __forceinline__ u16 f2b_n(float f){
  __hip_bfloat16 b = __float2bfloat16(f);
  return *reinterpret_cast<u16*>(&b);
}

__device__ __forceinline__ short8 cvt8v(f32x4 lo, f32x4 hi){
  short8 r;
  r[0]=(short)f2b_n(lo[0]); r[1]=(short)f2b_n(lo[1]); r[2]=(short)f2b_n(lo[2]); r[3]=(short)f2b_n(lo[3]);
  r[4]=(short)f2b_n(hi[0]); r[5]=(short)f2b_n(hi[1]); r[6]=(short)f2b_n(hi[2]); r[7]=(short)f2b_n(hi[3]);
  return r;
}

// ---------------- prep: k2/v2 = agent @ W + b ----------------
__global__ __launch_bounds__(256) void prep_kv(
    const float* __restrict__ agent_k, const float* __restrict__ Wk, const float* __restrict__ bk,
    const float* __restrict__ agent_v, const float* __restrict__ Wv, const float* __restrict__ bv,
    float* __restrict__ k2, float* __restrict__ v2)
{
  const int kv = blockIdx.x >> 6;
  const int c0 = (blockIdx.x & 63) * 8;
  const int t = threadIdx.x;
  const float* ag = kv ? agent_v : agent_k;
  const float* W  = kv ? Wv : Wk;
  const float* bb = kv ? bv : bk;
  float* dst      = kv ? v2 : k2;

  __shared__ float ash[16*512];
  __shared__ float part[32][16][8];

  for (int i = t; i < 8192; i += 256) ash[i] = ag[i];
  __syncthreads();
  const int cl = t & 7, ks = t >> 3;
  float s[16];
  #pragma unroll
  for (int a = 0; a < 16; ++a) s[a] = 0.f;
  #pragma unroll
  for (int i = 0; i < 16; ++i) {
    const int cc = ks*16 + i;
    const float wv = W[(size_t)cc*C_ + c0 + cl];
    #pragma unroll
    for (int a = 0; a < 16; ++a) s[a] += ash[a*512 + cc] * wv;
  }
  #pragma unroll
  for (int a = 0; a < 16; ++a) part[ks][a][cl] = s[a];
  __syncthreads();
  if (t < 128) {
    const int a = t >> 3, c = t & 7;
    float v = bb[c0 + c];
    #pragma unroll
    for (int k = 0; k < 32; ++k) v += part[k][a][c];
    dst[a*C_ + c0 + c] = v;
  }
}

// merged: blocks 0..511 -> WqkTr, blocks 512..639 -> WvpTr
__global__ __launch_bounds__(256) void prep_w(
    const float* __restrict__ Wq, const float* __restrict__ bq, const float* __restrict__ k2,
    const float* __restrict__ Wp, const float* __restrict__ v2,
    u16* __restrict__ WqkTr, float* __restrict__ bqk, u16* __restrict__ WvpTr)
{
  const int bx = blockIdx.x;
  if (bx < 512) {
    const int t = threadIdx.x;
    if (t < 128) {
      const int c = bx, h = t >> 4, a = t & 15;
      const f32x4* wq4 = (const f32x4*)(Wq + (size_t)c*C_ + h*64);
      const f32x4* k24 = (const f32x4*)(k2 + (size_t)a*C_ + h*64);
      float s = 0.f;
      #pragma unroll
      for (int d4 = 0; d4 < 16; ++d4) {
        f32x4 wv = wq4[d4], kv = k24[d4];
        s += wv[0]*kv[0] + wv[1]*kv[1] + wv[2]*kv[2] + wv[3]*kv[3];
      }
      const int kt = c >> 5, rg = (c >> 3) & 3, e = c & 7;
      const int ct = t >> 4, la = t & 15;
      WqkTr[(((kt*8 + ct)*64) + rg*16 + la)*8 + e] = f2b(s * 0.125f);
      if (c == 0){
        const f32x4* bq4 = (const f32x4*)(bq + h*64);
        float sb = 0.f;
        #pragma unroll
        for (int d4 = 0; d4 < 16; ++d4) {
          f32x4 wv = bq4[d4], kv = k24[d4];
          sb += wv[0]*kv[0] + wv[1]*kv[1] + wv[2]*kv[2] + wv[3]*kv[3];
        }
        bqk[t] = sb * 0.125f;
      }
    }
  } else {
    __shared__ float vsh[64];
    const int ha = bx - 512, h = ha >> 4, a = ha & 15;
    if (threadIdx.x < 64) vsh[threadIdx.x] = v2[a*C_ + h*64 + threadIdx.x];
    __syncthreads();
    const int kt = ha >> 5, rg = (ha >> 3) & 3, e = ha & 7;
    for (int co = threadIdx.x; co < C_; co += 256){
      float s = 0.f;
      #pragma unroll
      for (int d = 0; d < 64; ++d) s += vsh[d] * Wp[(size_t)(h*64 + d)*C_ + co];
      const int cb = co >> 7, ct = (co >> 4) & 7, la = co & 15;
      WvpTr[((((cb*4 + kt)*8 + ct)*64) + rg*16 + la)*8 + e] = f2b(s);
    }
  }
}

// ---------------- pass A: r8-validated — fragment-linear B in LDS, plain loads, no fence ----------------
__global__ __launch_bounds__(256, 4) void pass_a(
    const float* __restrict__ x, const u16* __restrict__ WqkTr,
    const float* __restrict__ bqk, u16* __restrict__ attn,
    float* __restrict__ gpart)
{
  __shared__ __align__(16) u16 Bs[16384];
  __shared__ float ps[4][16], pm[4][16];

  const int t = threadIdx.x;
  const int m0 = blockIdx.x * 128;
  const int w = t >> 6, lane = t & 63;
  const int la = lane & 15, rg = lane >> 4;

  const float* xr0 = x + (size_t)(m0 + w*32 + la)*C_ + rg*8;
  const float* xr1 = xr0 + 16*C_;

  f32x4 acc[2][8];
  #pragma unroll
  for (int i = 0; i < 2; ++i)
    #pragma unroll
    for (int j = 0; j < 8; ++j) acc[i][j] = (f32x4){0.f,0.f,0.f,0.f};

  f32x4 pr0[2][2], pr1[2][2];
#define LOADKT(slot, kt) \
  pr0[slot][0] = *(const f32x4*)(xr0 + (kt)*32);     \
  pr0[slot][1] = *(const f32x4*)(xr0 + (kt)*32 + 4); \
  pr1[slot][0] = *(const f32x4*)(xr1 + (kt)*32);     \
  pr1[slot][1] = *(const f32x4*)(xr1 + (kt)*32 + 4);

  LOADKT(0, 0); LOADKT(1, 1);

  #pragma unroll
  for (int ph = 0; ph < 4; ++ph) {
    __syncthreads();
    {
      const short8* gs = (const short8*)WqkTr + ph*2048 + t;
      short8* ld = (short8*)Bs + t;
      #pragma unroll
      for (int i = 0; i < 8; ++i) ld[i*256] = gs[i*256];
    }
    __syncthreads();
    #pragma unroll
    for (int k4 = 0; k4 < 4; ++k4) {
      const int kt = ph*4 + k4;
      const int sl = kt & 1;
      short8 b0 = cvt8v(pr0[sl][0], pr0[sl][1]);
      short8 b1 = cvt8v(pr1[sl][0], pr1[sl][1]);
      if (kt < 14) { LOADKT(sl, kt + 2); }
      const u16* fb = Bs + (size_t)k4*4096 + lane*8;
      #pragma unroll
      for (int ct = 0; ct < 8; ++ct) {
        short8 af = *(const short8*)(fb + ct*512);
        acc[0][ct] = __builtin_amdgcn_mfma_f32_16x16x32_bf16(af, b0, acc[0][ct], 0, 0, 0);
        acc[1][ct] = __builtin_amdgcn_mfma_f32_16x16x32_bf16(af, b1, acc[1][ct], 0, 0, 0);
      }
    }
  }
#undef LOADKT

  float psj[4] = {0.f,0.f,0.f,0.f};
  float pmj[4] = {0.f,0.f,0.f,0.f};

  #pragma unroll
  for (int nt = 0; nt < 2; ++nt) {
    const int row = m0 + w*32 + nt*16 + la;
    #pragma unroll
    for (int ct = 0; ct < 8; ++ct) {
      const f32x4 bb = *(const f32x4*)(bqk + ct*16 + rg*4);
      float e0 = __expf(acc[nt][ct][0] + bb[0]);
      float e1 = __expf(acc[nt][ct][1] + bb[1]);
      float e2 = __expf(acc[nt][ct][2] + bb[2]);
      float e3 = __expf(acc[nt][ct][3] + bb[3]);
      float s = e0 + e1 + e2 + e3;
      s += __shfl_xor(s, 16); s += __shfl_xor(s, 32);
      float r = __builtin_amdgcn_rcpf(s);
      float p0 = e0*r, p1 = e1*r, p2 = e2*r, p3 = e3*r;
      psj[0] += p0; psj[1] += p1; psj[2] += p2; psj[3] += p3;
      pmj[0] = fmaxf(pmj[0], p0); pmj[1] = fmaxf(pmj[1], p1);
      pmj[2] = fmaxf(pmj[2], p2); pmj[3] = fmaxf(pmj[3], p3);
      short4_t st;
      st[0]=(short)f2b(p0); st[1]=(short)f2b(p1); st[2]=(short)f2b(p2); st[3]=(short)f2b(p3);
      *(short4_t*)(attn + (size_t)row*128 + ct*16 + rg*4) = st;
    }
  }

  #pragma unroll
  for (int j = 0; j < 4; ++j) {
    float s = psj[j], m = pmj[j];
    s += __shfl_xor(s, 1); s += __shfl_xor(s, 2); s += __shfl_xor(s, 4); s += __shfl_xor(s, 8);
    m = fmaxf(m, __shfl_xor(m, 1)); m = fmaxf(m, __shfl_xor(m, 2));
    m = fmaxf(m, __shfl_xor(m, 4)); m = fmaxf(m, __shfl_xor(m, 8));
    if (la == 0) { ps[w][rg*4+j] = s; pm[w][rg*4+j] = m; }
  }
  __syncthreads();
  if (t < 16) {
    float s = ps[0][t] + ps[1][t] + ps[2][t] + ps[3][t];
    float m = fmaxf(fmaxf(pm[0][t], pm[1][t]), fmaxf(pm[2][t], pm[3][t]));
    gpart[(size_t)blockIdx.x*32 + t]      = s;
    gpart[(size_t)blockIdx.x*32 + 16 + t] = m;
  }
}

// ---------------- pass B: 1024 blocks, attn read ONCE, gate in prologue, plain mem ops ----------------
__global__ __launch_bounds__(256, 4) void pass_b(
    const u16* __restrict__ attn, const u16* __restrict__ WvpTr,
    const float* __restrict__ gpart, const float* __restrict__ ca_w1,
    const float* __restrict__ ca_w2, const float* __restrict__ bp,
    float* __restrict__ out)
{
  __shared__ __align__(16) u16 Bs[16384];
  __shared__ float gsh[16];
  const int bx = blockIdx.x;
  const int mb = (bx & 7)*128 + (bx >> 3);   // XCD swizzle over 1024
  const int b = mb >> 5;
  const int t = threadIdx.x;
  const int w = t >> 6, lane = t & 63;
  const int la = lane & 15, rg = lane >> 4;

  // attn fragments once
  const u16* br0 = attn + (size_t)(mb*128 + w*32 + la)*128 + rg*8;
  const u16* br1 = br0 + 16*128;
  short8 bf0[4], bf1[4];
  #pragma unroll
  for (int kt = 0; kt < 4; ++kt) {
    bf0[kt] = *(const short8*)(br0 + kt*32);
    bf1[kt] = *(const short8*)(br1 + kt*32);
  }

  // gate MLP from per-block partials (t<16)
  if (t < 16) {
    float s = 0.f, m = 0.f;
    #pragma unroll 4
    for (int blk = 0; blk < 32; ++blk) {
      const float* gp = gpart + (size_t)(b*32 + blk)*32;
      s += gp[t]; m = fmaxf(m, gp[16 + t]);
    }
    float c1 = s * (1.0f/32768.0f) * ca_w1[t];
    float c2 = m * ca_w1[t];
    c1 += __shfl_xor(c1, 1); c1 += __shfl_xor(c1, 2); c1 += __shfl_xor(c1, 4); c1 += __shfl_xor(c1, 8);
    c2 += __shfl_xor(c2, 1); c2 += __shfl_xor(c2, 2); c2 += __shfl_xor(c2, 4); c2 += __shfl_xor(c2, 8);
    float g1 = fmaxf(c1, 0.f) + fmaxf(c2, 0.f);
    gsh[t] = 1.f / (1.f + __expf(-g1 * ca_w2[t]));
  }
  __syncthreads();

  // gate folded into P-fragments once: k&15 = (rg&1)*8 + e
  float ge[8];
  #pragma unroll
  for (int e = 0; e < 8; ++e) ge[e] = gsh[(rg & 1)*8 + e];
  #pragma unroll
  for (int kt = 0; kt < 4; ++kt) {
    short8 v0 = bf0[kt], v1 = bf1[kt];
    #pragma unroll
    for (int e = 0; e < 8; ++e) {
      v0[e] = (short)f2b(b2f((u16)v0[e]) * ge[e]);
      v1[e] = (short)f2b(b2f((u16)v1[e]) * ge[e]);
    }
    bf0[kt] = v0; bf1[kt] = v1;
  }

  #pragma unroll 1
  for (int cb = 0; cb < 4; ++cb) {
    if (cb) __syncthreads();               // prior cb's LDS reads complete
    {
      const short8* gs = (const short8*)WvpTr + cb*2048 + t;
      short8* ld = (short8*)Bs + t;
      #pragma unroll
      for (int i = 0; i < 8; ++i) ld[i*256] = gs[i*256];
    }
    __syncthreads();

    f32x4 acc[2][8];
    #pragma unroll
    for (int i = 0; i < 2; ++i)
      #pragma unroll
      for (int j = 0; j < 8; ++j) acc[i][j] = (f32x4){0.f,0.f,0.f,0.f};

    #pragma unroll
    for (int kt = 0; kt < 4; ++kt) {
      const u16* fb = Bs + (size_t)kt*4096 + lane*8;
      #pragma unroll
      for (int ct = 0; ct < 8; ++ct) {
        short8 af = *(const short8*)(fb + ct*512);
        acc[0][ct] = __builtin_amdgcn_mfma_f32_16x16x32_bf16(af, bf0[kt], acc[0][ct], 0, 0, 0);
        acc[1][ct] = __builtin_amdgcn_mfma_f32_16x16x32_bf16(af, bf1[kt], acc[1][ct], 0, 0, 0);
      }
    }

    #pragma unroll
    for (int nt = 0; nt < 2; ++nt) {
      const size_t row = (size_t)(mb*128 + w*32 + nt*16 + la);
      #pragma unroll
      for (int ct = 0; ct < 8; ++ct) {
        const int col = cb*128 + ct*16 + rg*4;
        const f32x4 bb = *(const f32x4*)(bp + col);
        f32x4 o;
        o[0] = acc[nt][ct][0] + bb[0];
        o[1] = acc[nt][ct][1] + bb[1];
        o[2] = acc[nt][ct][2] + bb[2];
        o[3] = acc[nt][ct][3] + bb[3];
        *(f32x4*)(out + row*C_ + col) = o;
      }
    }
  }
}

// ---------------- launch ----------------
extern "C" void kernel_launch(void* const* d_in, const int* in_sizes, int n_in,
                              void* d_out, int out_size, void* d_ws, size_t ws_size,
                              hipStream_t stream)
{
  const float* x       = (const float*)d_in[0];
  const float* Wq      = (const float*)d_in[1];
  const float* bq      = (const float*)d_in[2];
  const float* Wk      = (const float*)d_in[3];
  const float* bk      = (const float*)d_in[4];
  const float* Wv      = (const float*)d_in[5];
  const float* bv      = (const float*)d_in[6];
  const float* Wp      = (const float*)d_in[7];
  const float* bp      = (const float*)d_in[8];
  const float* agent_k = (const float*)d_in[9];
  const float* agent_v = (const float*)d_in[10];
  const float* ca_w1   = (const float*)d_in[11];
  const float* ca_w2   = (const float*)d_in[12];
  float* out = (float*)d_out;

  char* ws = (char*)d_ws;
  u16*   attn   = (u16*)(ws);                          // 33,554,432 B
  float* k2     = (float*)(ws + 33554432);             // 32768
  float* v2     = (float*)(ws + 33587200);             // 32768
  u16*   WqkTr  = (u16*)(ws + 33619968);               // 131072
  float* bqk    = (float*)(ws + 33751040);             // 2048
  u16*   WvpTr  = (u16*)(ws + 33753088);               // 131072
  float* gpart  = (float*)(ws + 33884160);             // 131072

  prep_kv<<<128, 256, 0, stream>>>(agent_k, Wk, bk, agent_v, Wv, bv, k2, v2);
  prep_w<<<640, 256, 0, stream>>>(Wq, bq, k2, Wp, v2, WqkTr, bqk, WvpTr);
  pass_a<<<1024, 256, 0, stream>>>(x, WqkTr, bqk, attn, gpart);
  pass_b<<<1024, 256, 0, stream>>>(attn, WvpTr, gpart, ca_w1, ca_w2, bp, out);
}

// Round 16
// 215.555 us; speedup vs baseline: 3.4455x; 1.0783x over previous
//
#include <hip/hip_runtime.h>
#include <hip/hip_bf16.h>
#include <stdint.h>

typedef __attribute__((ext_vector_type(8))) short short8;
typedef __attribute__((ext_vector_type(4))) short short4_t;
typedef __attribute__((ext_vector_type(4))) float f32x4;
typedef unsigned short u16;
typedef unsigned int u32;

#define C_ 512

__device__ __forceinline__ u16 f2b(float f){
  u32 u = __float_as_uint(f);
  u += 0x7FFFu + ((u >> 16) & 1u);
  return (u16)(u >> 16);
}
__device__ __forceinline__ float b2f(u16 h){ return __uint_as_float(((u32)h) << 16); }

__device__ __forceinline__ u16 f2b_n(float f){
  __hip_bfloat16 b = __float2bfloat16(f);
  return *reinterpret_cast<u16*>(&b);
}

__device__ __forceinline__ short8 cvt8v(f32x4 lo, f32x4 hi){
  short8 r;
  r[0]=(short)f2b_n(lo[0]); r[1]=(short)f2b_n(lo[1]); r[2]=(short)f2b_n(lo[2]); r[3]=(short)f2b_n(lo[3]);
  r[4]=(short)f2b_n(hi[0]); r[5]=(short)f2b_n(hi[1]); r[6]=(short)f2b_n(hi[2]); r[7]=(short)f2b_n(hi[3]);
  return r;
}

// ---------------- prep: k2/v2 = agent @ W + b ----------------
__global__ __launch_bounds__(256) void prep_kv(
    const float* __restrict__ agent_k, const float* __restrict__ Wk, const float* __restrict__ bk,
    const float* __restrict__ agent_v, const float* __restrict__ Wv, const float* __restrict__ bv,
    float* __restrict__ k2, float* __restrict__ v2)
{
  const int kv = blockIdx.x >> 6;
  const int c0 = (blockIdx.x & 63) * 8;
  const int t = threadIdx.x;
  const float* ag = kv ? agent_v : agent_k;
  const float* W  = kv ? Wv : Wk;
  const float* bb = kv ? bv : bk;
  float* dst      = kv ? v2 : k2;

  __shared__ float ash[16*512];
  __shared__ float part[32][16][8];

  for (int i = t; i < 8192; i += 256) ash[i] = ag[i];
  __syncthreads();
  const int cl = t & 7, ks = t >> 3;
  float s[16];
  #pragma unroll
  for (int a = 0; a < 16; ++a) s[a] = 0.f;
  #pragma unroll
  for (int i = 0; i < 16; ++i) {
    const int cc = ks*16 + i;
    const float wv = W[(size_t)cc*C_ + c0 + cl];
    #pragma unroll
    for (int a = 0; a < 16; ++a) s[a] += ash[a*512 + cc] * wv;
  }
  #pragma unroll
  for (int a = 0; a < 16; ++a) part[ks][a][cl] = s[a];
  __syncthreads();
  if (t < 128) {
    const int a = t >> 3, c = t & 7;
    float v = bb[c0 + c];
    #pragma unroll
    for (int k = 0; k < 32; ++k) v += part[k][a][c];
    dst[a*C_ + c0 + c] = v;
  }
}

// merged: blocks 0..511 -> WqkTr, blocks 512..639 -> WvpTr
__global__ __launch_bounds__(256) void prep_w(
    const float* __restrict__ Wq, const float* __restrict__ bq, const float* __restrict__ k2,
    const float* __restrict__ Wp, const float* __restrict__ v2,
    u16* __restrict__ WqkTr, float* __restrict__ bqk, u16* __restrict__ WvpTr)
{
  const int bx = blockIdx.x;
  if (bx < 512) {
    const int t = threadIdx.x;
    if (t < 128) {
      const int c = bx, h = t >> 4, a = t & 15;
      const f32x4* wq4 = (const f32x4*)(Wq + (size_t)c*C_ + h*64);
      const f32x4* k24 = (const f32x4*)(k2 + (size_t)a*C_ + h*64);
      float s = 0.f;
      #pragma unroll
      for (int d4 = 0; d4 < 16; ++d4) {
        f32x4 wv = wq4[d4], kv = k24[d4];
        s += wv[0]*kv[0] + wv[1]*kv[1] + wv[2]*kv[2] + wv[3]*kv[3];
      }
      const int kt = c >> 5, rg = (c >> 3) & 3, e = c & 7;
      const int ct = t >> 4, la = t & 15;
      WqkTr[(((kt*8 + ct)*64) + rg*16 + la)*8 + e] = f2b(s * 0.125f);
      if (c == 0){
        const f32x4* bq4 = (const f32x4*)(bq + h*64);
        float sb = 0.f;
        #pragma unroll
        for (int d4 = 0; d4 < 16; ++d4) {
          f32x4 wv = bq4[d4], kv = k24[d4];
          sb += wv[0]*kv[0] + wv[1]*kv[1] + wv[2]*kv[2] + wv[3]*kv[3];
        }
        bqk[t] = sb * 0.125f;
      }
    }
  } else {
    __shared__ float vsh[64];
    const int ha = bx - 512, h = ha >> 4, a = ha & 15;
    if (threadIdx.x < 64) vsh[threadIdx.x] = v2[a*C_ + h*64 + threadIdx.x];
    __syncthreads();
    const int kt = ha >> 5, rg = (ha >> 3) & 3, e = ha & 7;
    for (int co = threadIdx.x; co < C_; co += 256){
      float s = 0.f;
      #pragma unroll
      for (int d = 0; d < 64; ++d) s += vsh[d] * Wp[(size_t)(h*64 + d)*C_ + co];
      const int cb = co >> 7, ct = (co >> 4) & 7, la = co & 15;
      WvpTr[((((cb*4 + kt)*8 + ct)*64) + rg*16 + la)*8 + e] = f2b(s);
    }
  }
}

// ---------------- pass A: 64-row tiles, 2048 blocks, 32KB LDS exact, 5 blocks/CU ----------------
__global__ __launch_bounds__(256, 5) void pass_a(
    const float* __restrict__ x, const u16* __restrict__ WqkTr,
    const float* __restrict__ bqk, u16* __restrict__ attn,
    float* __restrict__ gpart)
{
  __shared__ __align__(16) u16 Bs[16384];   // 32 KB exact; ps/pm aliased post-K-loop

  const int t = threadIdx.x;
  const int m0 = blockIdx.x * 64;
  const int w = t >> 6, lane = t & 63;
  const int la = lane & 15, rg = lane >> 4;

  const float* xr = x + (size_t)(m0 + w*16 + la)*C_ + rg*8;

  f32x4 acc[8];
  #pragma unroll
  for (int j = 0; j < 8; ++j) acc[j] = (f32x4){0.f,0.f,0.f,0.f};

  f32x4 pr[2][2];                           // depth-2 kt ring (16 VGPR)
#define LOADKT(slot, kt) \
  pr[slot][0] = *(const f32x4*)(xr + (kt)*32);     \
  pr[slot][1] = *(const f32x4*)(xr + (kt)*32 + 4);

  LOADKT(0, 0); LOADKT(1, 1);

  #pragma unroll
  for (int ph = 0; ph < 4; ++ph) {
    __syncthreads();
    {
      const short8* gs = (const short8*)WqkTr + ph*2048 + t;
      short8* ld = (short8*)Bs + t;
      #pragma unroll
      for (int i = 0; i < 8; ++i) ld[i*256] = gs[i*256];
    }
    __syncthreads();
    #pragma unroll
    for (int k4 = 0; k4 < 4; ++k4) {
      const int kt = ph*4 + k4;
      const int sl = kt & 1;
      short8 b0 = cvt8v(pr[sl][0], pr[sl][1]);
      if (kt < 14) { LOADKT(sl, kt + 2); }
      const u16* fb = Bs + (size_t)k4*4096 + lane*8;
      #pragma unroll
      for (int ct = 0; ct < 8; ++ct) {
        short8 af = *(const short8*)(fb + ct*512);
        acc[ct] = __builtin_amdgcn_mfma_f32_16x16x32_bf16(af, b0, acc[ct], 0, 0, 0);
      }
    }
  }
#undef LOADKT

  // epilogue: softmax over a (in-register) + attn write + gating partials
  float psj[4] = {0.f,0.f,0.f,0.f};
  float pmj[4] = {0.f,0.f,0.f,0.f};
  const int row = m0 + w*16 + la;

  #pragma unroll
  for (int ct = 0; ct < 8; ++ct) {
    const f32x4 bb = *(const f32x4*)(bqk + ct*16 + rg*4);
    float e0 = __expf(acc[ct][0] + bb[0]);
    float e1 = __expf(acc[ct][1] + bb[1]);
    float e2 = __expf(acc[ct][2] + bb[2]);
    float e3 = __expf(acc[ct][3] + bb[3]);
    float s = e0 + e1 + e2 + e3;
    s += __shfl_xor(s, 16); s += __shfl_xor(s, 32);
    float r = __builtin_amdgcn_rcpf(s);
    float p0 = e0*r, p1 = e1*r, p2 = e2*r, p3 = e3*r;
    psj[0] += p0; psj[1] += p1; psj[2] += p2; psj[3] += p3;
    pmj[0] = fmaxf(pmj[0], p0); pmj[1] = fmaxf(pmj[1], p1);
    pmj[2] = fmaxf(pmj[2], p2); pmj[3] = fmaxf(pmj[3], p3);
    short4_t st;
    st[0]=(short)f2b(p0); st[1]=(short)f2b(p1); st[2]=(short)f2b(p2); st[3]=(short)f2b(p3);
    *(short4_t*)(attn + (size_t)row*128 + ct*16 + rg*4) = st;
  }

  __syncthreads();                          // all Bs reads done -> safe to alias ps/pm
  float* psm = (float*)Bs;                  // [0..63]=ps(w,idx), [64..127]=pm(w,idx)
  #pragma unroll
  for (int j = 0; j < 4; ++j) {
    float s = psj[j], m = pmj[j];
    s += __shfl_xor(s, 1); s += __shfl_xor(s, 2); s += __shfl_xor(s, 4); s += __shfl_xor(s, 8);
    m = fmaxf(m, __shfl_xor(m, 1)); m = fmaxf(m, __shfl_xor(m, 2));
    m = fmaxf(m, __shfl_xor(m, 4)); m = fmaxf(m, __shfl_xor(m, 8));
    if (la == 0) { psm[w*16 + rg*4 + j] = s; psm[64 + w*16 + rg*4 + j] = m; }
  }
  __syncthreads();
  if (t < 16) {
    float s = psm[t] + psm[16 + t] + psm[32 + t] + psm[48 + t];
    float m = fmaxf(fmaxf(psm[64 + t], psm[80 + t]), fmaxf(psm[96 + t], psm[112 + t]));
    gpart[(size_t)blockIdx.x*32 + t]      = s;
    gpart[(size_t)blockIdx.x*32 + 16 + t] = m;
  }
}

// ---------------- pass B: 64-row tiles, 2048 blocks, attn read once, 32KB LDS exact ----------------
__global__ __launch_bounds__(256, 5) void pass_b(
    const u16* __restrict__ attn, const u16* __restrict__ WvpTr,
    const float* __restrict__ gpart, const float* __restrict__ ca_w1,
    const float* __restrict__ ca_w2, const float* __restrict__ bp,
    float* __restrict__ out)
{
  __shared__ __align__(16) u16 Bs[16384];   // 32 KB; gsh aliased pre-staging
  const int bx = blockIdx.x;
  const int mb = (bx & 7)*256 + (bx >> 3);  // XCD swizzle over 2048
  const int b = mb >> 6;
  const int t = threadIdx.x;
  const int w = t >> 6, lane = t & 63;
  const int la = lane & 15, rg = lane >> 4;
  const int row = mb*64 + w*16 + la;

  // attn fragments once
  const u16* br = attn + (size_t)row*128 + rg*8;
  short8 bf[4];
  #pragma unroll
  for (int kt = 0; kt < 4; ++kt) bf[kt] = *(const short8*)(br + kt*32);

  // gate MLP from per-block partials (t<16), gsh aliased onto Bs
  float* ga = (float*)Bs;
  if (t < 16) {
    float s = 0.f, m = 0.f;
    #pragma unroll 4
    for (int blk = 0; blk < 64; ++blk) {
      const float* gp = gpart + (size_t)(b*64 + blk)*32;
      s += gp[t]; m = fmaxf(m, gp[16 + t]);
    }
    float c1 = s * (1.0f/32768.0f) * ca_w1[t];
    float c2 = m * ca_w1[t];
    c1 += __shfl_xor(c1, 1); c1 += __shfl_xor(c1, 2); c1 += __shfl_xor(c1, 4); c1 += __shfl_xor(c1, 8);
    c2 += __shfl_xor(c2, 1); c2 += __shfl_xor(c2, 2); c2 += __shfl_xor(c2, 4); c2 += __shfl_xor(c2, 8);
    float g1 = fmaxf(c1, 0.f) + fmaxf(c2, 0.f);
    ga[t] = 1.f / (1.f + __expf(-g1 * ca_w2[t]));
  }
  __syncthreads();

  // gate folded into P-fragments once: k&15 = (rg&1)*8 + e
  float ge[8];
  #pragma unroll
  for (int e = 0; e < 8; ++e) ge[e] = ga[(rg & 1)*8 + e];
  #pragma unroll
  for (int kt = 0; kt < 4; ++kt) {
    short8 v0 = bf[kt];
    #pragma unroll
    for (int e = 0; e < 8; ++e) v0[e] = (short)f2b(b2f((u16)v0[e]) * ge[e]);
    bf[kt] = v0;
  }

  #pragma unroll 1
  for (int cb = 0; cb < 4; ++cb) {
    __syncthreads();                        // gsh consumed / prior cb reads done
    {
      const short8* gs = (const short8*)WvpTr + cb*2048 + t;
      short8* ld = (short8*)Bs + t;
      #pragma unroll
      for (int i = 0; i < 8; ++i) ld[i*256] = gs[i*256];
    }
    __syncthreads();

    f32x4 acc[8];
    #pragma unroll
    for (int j = 0; j < 8; ++j) acc[j] = (f32x4){0.f,0.f,0.f,0.f};

    #pragma unroll
    for (int kt = 0; kt < 4; ++kt) {
      const u16* fb = Bs + (size_t)kt*4096 + lane*8;
      #pragma unroll
      for (int ct = 0; ct < 8; ++ct) {
        short8 af = *(const short8*)(fb + ct*512);
        acc[ct] = __builtin_amdgcn_mfma_f32_16x16x32_bf16(af, bf[kt], acc[ct], 0, 0, 0);
      }
    }

    #pragma unroll
    for (int ct = 0; ct < 8; ++ct) {
      const int col = cb*128 + ct*16 + rg*4;
      const f32x4 bb = *(const f32x4*)(bp + col);
      f32x4 o;
      o[0] = acc[ct][0] + bb[0];
      o[1] = acc[ct][1] + bb[1];
      o[2] = acc[ct][2] + bb[2];
      o[3] = acc[ct][3] + bb[3];
      *(f32x4*)(out + (size_t)row*C_ + col) = o;
    }
  }
}

// ---------------- launch ----------------
extern "C" void kernel_launch(void* const* d_in, const int* in_sizes, int n_in,
                              void* d_out, int out_size, void* d_ws, size_t ws_size,
                              hipStream_t stream)
{
  const float* x       = (const float*)d_in[0];
  const float* Wq      = (const float*)d_in[1];
  const float* bq      = (const float*)d_in[2];
  const float* Wk      = (const float*)d_in[3];
  const float* bk      = (const float*)d_in[4];
  const float* Wv      = (const float*)d_in[5];
  const float* bv      = (const float*)d_in[6];
  const float* Wp      = (const float*)d_in[7];
  const float* bp      = (const float*)d_in[8];
  const float* agent_k = (const float*)d_in[9];
  const float* agent_v = (const float*)d_in[10];
  const float* ca_w1   = (const float*)d_in[11];
  const float* ca_w2   = (const float*)d_in[12];
  float* out = (float*)d_out;

  char* ws = (char*)d_ws;
  u16*   attn   = (u16*)(ws);                          // 33,554,432 B
  float* k2     = (float*)(ws + 33554432);             // 32768
  float* v2     = (float*)(ws + 33587200);             // 32768
  u16*   WqkTr  = (u16*)(ws + 33619968);               // 131072
  float* bqk    = (float*)(ws + 33751040);             // 2048
  u16*   WvpTr  = (u16*)(ws + 33753088);               // 131072
  float* gpart  = (float*)(ws + 33884160);             // 2048*32*4 = 262144

  prep_kv<<<128, 256, 0, stream>>>(agent_k, Wk, bk, agent_v, Wv, bv, k2, v2);
  prep_w<<<640, 256, 0, stream>>>(Wq, bq, k2, Wp, v2, WqkTr, bqk, WvpTr);
  pass_a<<<2048, 256, 0, stream>>>(x, WqkTr, bqk, attn, gpart);
  pass_b<<<2048, 256, 0, stream>>>(attn, WvpTr, gpart, ca_w1, ca_w2, bp, out);
}